// Round 22
// baseline (284.312 us; speedup 1.0000x reference)
//
#include <hip/hip_runtime.h>
#include <hip/hip_bf16.h>

using bf16 = __hip_bfloat16;
typedef unsigned int uint;
typedef unsigned short ushort;
typedef __attribute__((ext_vector_type(8))) short bf16x8;
typedef __attribute__((ext_vector_type(4))) float f32x4;

// Shapes: B=2, S=512, SD=512, P=256, PD=128, AD=64, H=256
// All global tensors are f32.

__device__ __forceinline__ float bfraw(uint u) { return __uint_as_float(u << 16); }
__device__ __forceinline__ ushort f2bf(float f) {
    bf16 h = __float2bfloat16(f);
    return *reinterpret_cast<ushort*>(&h);
}
__device__ __forceinline__ float lbf(ushort u) { return __uint_as_float(((uint)u) << 16); }

#define MFMA_B16(a, b, c) __builtin_amdgcn_mfma_f32_16x16x32_bf16((a), (b), (c), 0, 0, 0)
#define LGKM0() asm volatile("s_waitcnt lgkmcnt(0)" ::: "memory")

// ---------------------------------------------------------------------------
// A: LayerNorm(seq) over SD=512 + avg-pool row pairs -> x2 f32. 512 blocks.
// ---------------------------------------------------------------------------
__global__ __launch_bounds__(256) void k_ln_pool(
    const float* __restrict__ seq, const float* __restrict__ g,
    const float* __restrict__ be, float* __restrict__ x2)
{
    __shared__ float red[4][4];
    int bp = blockIdx.x;
    int t  = threadIdx.x;
    const float* r0 = seq + (size_t)(bp * 2) * 512;
    const float* r1 = r0 + 512;

    float a0 = r0[t], a1 = r0[t + 256];
    float c0 = r1[t], c1 = r1[t + 256];

    float s0 = a0 + a1, q0 = a0 * a0 + a1 * a1;
    float s1 = c0 + c1, q1 = c0 * c0 + c1 * c1;
#pragma unroll
    for (int off = 32; off; off >>= 1) {
        s0 += __shfl_xor(s0, off); q0 += __shfl_xor(q0, off);
        s1 += __shfl_xor(s1, off); q1 += __shfl_xor(q1, off);
    }
    int w = t >> 6, l = t & 63;
    if (l == 0) { red[0][w] = s0; red[1][w] = q0; red[2][w] = s1; red[3][w] = q1; }
    __syncthreads();
    s0 = red[0][0] + red[0][1] + red[0][2] + red[0][3];
    q0 = red[1][0] + red[1][1] + red[1][2] + red[1][3];
    s1 = red[2][0] + red[2][1] + red[2][2] + red[2][3];
    q1 = red[3][0] + red[3][1] + red[3][2] + red[3][3];

    const float inv = 1.0f / 512.0f;
    float mu0 = s0 * inv, var0 = q0 * inv - mu0 * mu0, rs0 = rsqrtf(var0 + 1e-5f);
    float mu1 = s1 * inv, var1 = q1 * inv - mu1 * mu1, rs1 = rsqrtf(var1 + 1e-5f);

    float g0 = g[t], g1 = g[t + 256];
    float e0 = be[t], e1 = be[t + 256];

    float o0 = 0.5f * ((a0 - mu0) * rs0 * g0 + e0 + (c0 - mu1) * rs1 * g0 + e0);
    float o1 = 0.5f * ((a1 - mu0) * rs0 * g1 + e1 + (c1 - mu1) * rs1 * g1 + e1);

    float* xo = x2 + (size_t)bp * 512;
    xo[t] = o0; xo[t + 256] = o1;
}

// ---------------------------------------------------------------------------
// B: A2 = (x@Wq + gelu(x)@Wyq)@Wout + bout ; C2 = (x@Wk + gelu(x)@Wyk)@Wout
// ---------------------------------------------------------------------------
__global__ __launch_bounds__(128) void k_proj(
    const float* __restrict__ x2,
    const float* __restrict__ Wq, const float* __restrict__ Wk,
    const float* __restrict__ Wyq, const float* __restrict__ Wyk,
    const float* __restrict__ Wout, const float* __restrict__ bout,
    float* __restrict__ a2, float* __restrict__ c2)
{
    __shared__ float xr[512], gxr[512], ar[128], cr[128];
    int row = blockIdx.x;
    int t   = threadIdx.x;

    for (int u = t; u < 512; u += 128) {
        float v = x2[(size_t)row * 512 + u];
        xr[u]  = v;
        gxr[u] = 0.5f * v * (1.0f + erff(v * 0.70710678118654752f));
    }
    __syncthreads();

    float a = 0.f, c = 0.f;
    for (int s = 0; s < 512; s++) {
        float xs = xr[s], gs = gxr[s];
        a += xs * Wq[s * 128 + t] + gs * Wyq[s * 128 + t];
        c += xs * Wk[s * 128 + t] + gs * Wyk[s * 128 + t];
    }
    ar[t] = a; cr[t] = c;
    __syncthreads();

    float A = bout[t], C = 0.f;
    for (int u = 0; u < 128; u++) {
        float wv = Wout[u * 128 + t];
        A += ar[u] * wv;
        C += cr[u] * wv;
    }
    a2[(size_t)row * 128 + t] = A;
    c2[(size_t)row * 128 + t] = C;
}

// ---------------------------------------------------------------------------
// W: Wd2 = Wdist(3x128) @ Wout(128x128)
// ---------------------------------------------------------------------------
__global__ __launch_bounds__(128) void k_wd2(
    const float* __restrict__ Wdist, const float* __restrict__ Wout,
    float* __restrict__ wd2)
{
    int t = threadIdx.x;
#pragma unroll
    for (int f = 0; f < 3; f++) {
        float acc = 0.f;
        for (int u = 0; u < 128; u++)
            acc += Wdist[f * 128 + u] * Wout[u * 128 + t];
        wd2[f * 128 + t] = acc;
    }
}

// ---------------------------------------------------------------------------
// WT prep (FRAGMENT-ORDER). m=0..2: Wrq/Wrk/Wrv; m=3: Wro.
// ---------------------------------------------------------------------------
__global__ __launch_bounds__(512) void k_wt(
    const float* __restrict__ Wrq, const float* __restrict__ Wrk,
    const float* __restrict__ Wrv, const float* __restrict__ Wro,
    ushort* __restrict__ wqF, ushort* __restrict__ wkF,
    ushort* __restrict__ wvF, ushort* __restrict__ wroF)
{
    int idx = blockIdx.x * 512 + threadIdx.x;       // 0 .. 4*8192
    int m = idx >> 13;
    int o = idx & 8191;
    int f = o >> 9;            // 0..15
    int l = (o >> 3) & 63;
    int j = o & 7;
    if (m < 3) {
        int nt = f >> 2, kf = f & 3;
        const float* W = (m == 0) ? Wrq : (m == 1) ? Wrk : Wrv;
        ushort* T = (m == 0) ? wqF : (m == 1) ? wkF : wvF;
        T[o] = f2bf(W[(32 * kf + 8 * (l >> 4) + j) * 64 + 16 * nt + (l & 15)]);
    } else {
        int nt = f >> 1, kf2 = f & 1;
        wroF[o] = f2bf(Wro[(32 * kf2 + 8 * (l >> 4) + j) * 128 + 16 * nt + (l & 15)]);
    }
}

// ---------------------------------------------------------------------------
// WT prep 2 (MLP, FRAGMENT-ORDER)
// ---------------------------------------------------------------------------
__global__ __launch_bounds__(512) void k_wt12(
    const float* __restrict__ W1, const float* __restrict__ W2,
    ushort* __restrict__ w1F, ushort* __restrict__ w2F)
{
    int idx = blockIdx.x * 512 + threadIdx.x;   // 0 .. 65536
    int o = idx & 32767;
    int f = o >> 9;            // 0..63
    int l = (o >> 3) & 63;
    int j = o & 7;
    int kb = f >> 5, nt = (f >> 2) & 7, kf = f & 3;
    if (idx < 32768) {
        int R = 128 * kb + 16 * nt + (l & 15);
        int C = 32 * kf + 8 * (l >> 4) + j;
        w1F[o] = f2bf(W1[C * 256 + R]);
    } else {
        int R2 = 16 * nt + (l & 15);
        int C2 = 128 * kb + 32 * kf + 8 * (l >> 4) + j;
        w2F[o] = f2bf(W2[C2 * 128 + R2]);
    }
}

// ---------------------------------------------------------------------------
// C: assemble (FALLBACK path only)
// ---------------------------------------------------------------------------
__global__ __launch_bounds__(256) void k_assemble(
    const float* __restrict__ pair, const float* __restrict__ a2,
    const float* __restrict__ c2, const float* __restrict__ wd2,
    float* __restrict__ xout)
{
    size_t idx = (size_t)blockIdx.x * 256 + threadIdx.x;
    int d = (int)(idx & 127);
    size_t r = idx >> 7;
    int j = (int)(r & 255); r >>= 8;
    int i = (int)(r & 255);
    int b = (int)(r >> 8);

    float ds = fabsf((float)(i - j)) * (1.0f / 255.0f);
    float sg = (float)((i > j) - (i < j));
    float ex = __expf(-ds);

    float v = pair[idx]
            + a2[(size_t)(b * 256 + i) * 128 + d]
            + c2[(size_t)(b * 256 + j) * 128 + d]
            + ds * wd2[d] + sg * wd2[128 + d] + ex * wd2[256 + d];
    xout[idx] = v;
}

// ---------------------------------------------------------------------------
// QKV + ASSEMBLE (split path, fused; proven round 21).
// ---------------------------------------------------------------------------
__global__ __launch_bounds__(64, 2) void k_qkv_asm(
    float* __restrict__ x, const float* __restrict__ pair,
    const float* __restrict__ a2, const float* __restrict__ c2,
    const float* __restrict__ wd2,
    const float* __restrict__ rn_g, const float* __restrict__ rn_b,
    const ushort* __restrict__ wqF, const ushort* __restrict__ wkF,
    const ushort* __restrict__ wvF, const float* __restrict__ brv,
    ushort* __restrict__ qA, ushort* __restrict__ kB, ushort* __restrict__ vB)
{
    __shared__ __align__(16) unsigned char smem[12288];
    int l = threadIdx.x;
    int g = l >> 4, lr = l & 15;
    int s = blockIdx.x & 511;
    int c = blockIdx.x >> 9;
    size_t xbase = (size_t)s * 32768 + (size_t)(32 * c) * 128;

    {
        float gl0 = rn_g[l], gl1 = rn_g[l + 64];
        float el0 = rn_b[l], el1 = rn_b[l + 64];
        int b  = s >> 8;
        int ii = s & 255;
        float a20 = a2[(size_t)s * 128 + l];
        float a21 = a2[(size_t)s * 128 + l + 64];
        float wdA0 = wd2[l],       wdA1 = wd2[l + 64];
        float wdB0 = wd2[128 + l], wdB1 = wd2[128 + l + 64];
        float wdC0 = wd2[256 + l], wdC1 = wd2[256 + l + 64];
#pragma unroll
        for (int bb = 0; bb < 8; bb++) {
            float p0[4], p1[4], c20[4], c21[4];
#pragma unroll
            for (int rr = 0; rr < 4; rr++) {
                size_t ro = xbase + (size_t)(4 * bb + rr) * 128;
                p0[rr] = pair[ro + l]; p1[rr] = pair[ro + l + 64];
                int j = 32 * c + 4 * bb + rr;
                c20[rr] = c2[(size_t)(b * 256 + j) * 128 + l];
                c21[rr] = c2[(size_t)(b * 256 + j) * 128 + l + 64];
            }
#pragma unroll
            for (int rr = 0; rr < 4; rr++) {
                int rloc = 4 * bb + rr;
                int j = 32 * c + rloc;
                float dsv = fabsf((float)(ii - j)) * (1.0f / 255.0f);
                float sgv = (float)((ii > j) - (ii < j));
                float exv = __expf(-dsv);
                float x0 = p0[rr] + a20 + c20[rr] + dsv * wdA0 + sgv * wdB0 + exv * wdC0;
                float x1 = p1[rr] + a21 + c21[rr] + dsv * wdA1 + sgv * wdB1 + exv * wdC1;
                size_t ro = xbase + (size_t)rloc * 128;
                x[ro + l] = x0; x[ro + l + 64] = x1;
                float sS = x0 + x1, qS = x0 * x0 + x1 * x1;
#pragma unroll
                for (int off = 32; off; off >>= 1) { sS += __shfl_xor(sS, off); qS += __shfl_xor(qS, off); }
                float mu = sS * (1.0f / 128.0f);
                float var = qS * (1.0f / 128.0f) - mu * mu;
                float rs = rsqrtf(var + 1e-5f);
                int sw = (rloc & 7) << 4;
                *(ushort*)(smem + rloc * 256 + ((2 * l) ^ sw))        = f2bf((x0 - mu) * rs * gl0 + el0);
                *(ushort*)(smem + rloc * 256 + ((2 * (l + 64)) ^ sw)) = f2bf((x1 - mu) * rs * gl1 + el1);
            }
        }
    }
    LGKM0();

    bf16x8 afr[2][4];
#pragma unroll
    for (int mt = 0; mt < 2; mt++)
#pragma unroll
        for (int kf = 0; kf < 4; kf++) {
            int row = 16 * mt + lr;
            afr[mt][kf] = *(const bf16x8*)(smem + row * 256 + ((16 * g + 64 * kf) ^ ((row & 7) << 4)));
        }

    unsigned char* dscr = smem + 8192;

#pragma unroll
    for (int mqk = 0; mqk < 2; mqk++) {
        const ushort* wF = mqk ? wkF : wqF;
        ushort* dst = mqk ? kB : qA;
        float scale = mqk ? 1.0f : 0.125f;
#pragma unroll
        for (int mt = 0; mt < 2; mt++) {
#pragma unroll
            for (int nt = 0; nt < 4; nt++) {
                f32x4 acc = (f32x4){0.f, 0.f, 0.f, 0.f};
#pragma unroll
                for (int kf = 0; kf < 4; kf++) {
                    bf16x8 bfr = *(const bf16x8*)(wF + (((nt << 2) | kf) << 9) + (l << 3));
                    acc = MFMA_B16(afr[mt][kf], bfr, acc);
                }
                int col = lr + 16 * nt;
#pragma unroll
                for (int i = 0; i < 4; i++) {
                    int row = 4 * g + i + 16 * mt;
                    int ad = row * 128 + ((2 * col) ^ ((row & 7) << 4));
                    *(ushort*)(dscr + ad) = f2bf(acc[i] * scale);
                }
            }
        }
        LGKM0();
#pragma unroll
        for (int mt = 0; mt < 2; mt++)
#pragma unroll
            for (int kf2 = 0; kf2 < 2; kf2++) {
                int row = 16 * mt + lr;
                int rd = row * 128 + ((64 * kf2 + 16 * g) ^ ((row & 7) << 4));
                bf16x8 v = *(const bf16x8*)(dscr + rd);
                *(bf16x8*)(dst + ((size_t)((s * 16 + 2 * c + mt) * 2 + kf2) << 9) + (l << 3)) = v;
            }
        LGKM0();
    }

#pragma unroll
    for (int mt = 0; mt < 2; mt++) {
#pragma unroll
        for (int nt = 0; nt < 4; nt++) {
            f32x4 acc = (f32x4){0.f, 0.f, 0.f, 0.f};
#pragma unroll
            for (int kf = 0; kf < 4; kf++) {
                bf16x8 bfr = *(const bf16x8*)(wvF + (((nt << 2) | kf) << 9) + (l << 3));
                acc = MFMA_B16(afr[mt][kf], bfr, acc);
            }
            int d = lr + 16 * nt;
            float bv = brv[d];
#pragma unroll
            for (int i = 0; i < 4; i++) {
                int kk = 4 * g + i + 16 * mt;
                int ad = d * 64 + ((2 * kk) ^ ((d & 3) << 4));
                *(ushort*)(dscr + ad) = f2bf(acc[i] + bv);
            }
        }
    }
    LGKM0();
#pragma unroll
    for (int nt2 = 0; nt2 < 4; nt2++) {
        int d = 16 * nt2 + lr;
        int rd = d * 64 + ((16 * g) ^ ((d & 3) << 4));
        bf16x8 vv = *(const bf16x8*)(dscr + rd);
        *(bf16x8*)(vB + ((size_t)((s * 4 + nt2) * 8 + c) << 9) + (l << 3)) = vv;
    }
}

// ---------------------------------------------------------------------------
// Flash + out-proj + MLP (split path, FULLY FUSED): 2048 blocks x 128 threads
// (2 independent waves x 32 q-rows; private 10KB LDS region, zero barriers).
// Each wave owns its 32 rows completely, so after out-proj the MLP for those
// rows is self-contained: x_new kept in registers (static-indexed xn[2][8]),
// MLP-LN via 16-lane-group shuffles, yn bounced through the dead P region,
// v6 MLP GEMM with B-frags shared across the two 16-row tiles, final value
// written ONCE. Removes 134MB of x traffic + one dispatch vs round 21.
// launch_bounds (128,2): cap 256 VGPR >= est ~230; tripwire = WRITE_SIZE.
// LDS per wave: region0 [32][256B]=8KB (P -> O-bounce -> yn), region1 2KB (h).
// ---------------------------------------------------------------------------
__global__ __launch_bounds__(128, 2) void k_attn_mlp(
    float* __restrict__ x,
    const ushort* __restrict__ qA, const ushort* __restrict__ kB,
    const ushort* __restrict__ vB, const ushort* __restrict__ wroF,
    const float* __restrict__ bro,
    const float* __restrict__ mn_g, const float* __restrict__ mn_b,
    const ushort* __restrict__ w1F, const ushort* __restrict__ w2F,
    const float* __restrict__ b1, const float* __restrict__ b2)
{
    __shared__ __align__(16) unsigned char smem_all[20480];
    int tid = threadIdx.x;
    int w = tid >> 6;
    int l = tid & 63, g = l >> 4, lr = l & 15;
    int s = blockIdx.x & 511;               // slice (XCD-locality)
    int qc = ((blockIdx.x >> 9) << 1) | w;  // q-chunk 0..7
    unsigned char* smem = smem_all + w * 10240;   // region0 @0 (8KB), region1 @8192 (2KB)

    // ================= attention (round-18 proven structure) ================
    bf16x8 qf[2][2];
#pragma unroll
    for (int mt = 0; mt < 2; mt++)
#pragma unroll
        for (int kf2 = 0; kf2 < 2; kf2++)
            qf[mt][kf2] = *(const bf16x8*)(qA + ((size_t)((s * 16 + 2 * qc + mt) * 2 + kf2) << 9) + (l << 3));

    float m_run[2][4], l_run[2][4];
    f32x4 oacc[2][4];
#pragma unroll
    for (int mt = 0; mt < 2; mt++)
#pragma unroll
        for (int i = 0; i < 4; i++) { m_run[mt][i] = -INFINITY; l_run[mt][i] = 0.f; }
#pragma unroll
    for (int mt = 0; mt < 2; mt++)
#pragma unroll
        for (int nt = 0; nt < 4; nt++) oacc[mt][nt] = (f32x4){0.f, 0.f, 0.f, 0.f};

    for (int t = 0; t < 2; t++) {
        f32x4 sacc[2][8];
#pragma unroll
        for (int mt = 0; mt < 2; mt++)
#pragma unroll
            for (int nt = 0; nt < 8; nt++) sacc[mt][nt] = (f32x4){0.f, 0.f, 0.f, 0.f};
#pragma unroll
        for (int nt = 0; nt < 8; nt++) {
            int kt = 8 * t + nt;
#pragma unroll
            for (int kf2 = 0; kf2 < 2; kf2++) {
                bf16x8 kfr = *(const bf16x8*)(kB + ((size_t)((s * 16 + kt) * 2 + kf2) << 9) + (l << 3));
                sacc[0][nt] = MFMA_B16(qf[0][kf2], kfr, sacc[0][nt]);
                sacc[1][nt] = MFMA_B16(qf[1][kf2], kfr, sacc[1][nt]);
            }
        }
#pragma unroll
        for (int mt = 0; mt < 2; mt++) {
#pragma unroll
            for (int i = 0; i < 4; i++) {
                float mx = sacc[mt][0][i];
#pragma unroll
                for (int nt = 1; nt < 8; nt++) mx = fmaxf(mx, sacc[mt][nt][i]);
#pragma unroll
                for (int off = 1; off < 16; off <<= 1) mx = fmaxf(mx, __shfl_xor(mx, off));
                float mnew = fmaxf(m_run[mt][i], mx);
                float corr = __expf(m_run[mt][i] - mnew);
                m_run[mt][i] = mnew;
                int row = 16 * mt + 4 * g + i;
                int swp = (row & 7) << 4;
                float rs = 0.f;
#pragma unroll
                for (int nt = 0; nt < 8; nt++) {
                    float p = __expf(sacc[mt][nt][i] - mnew);
                    rs += p;
                    int key = lr + 16 * nt;
                    *(ushort*)(smem + row * 256 + ((2 * key) ^ swp)) = f2bf(p);
                }
#pragma unroll
                for (int off = 1; off < 16; off <<= 1) rs += __shfl_xor(rs, off);
                l_run[mt][i] = l_run[mt][i] * corr + rs;
#pragma unroll
                for (int nt = 0; nt < 4; nt++) oacc[mt][nt][i] *= corr;
            }
        }
        LGKM0();
#pragma unroll
        for (int kc = 0; kc < 4; kc++) {
            bf16x8 pfr[2];
#pragma unroll
            for (int mt = 0; mt < 2; mt++) {
                int prow = 16 * mt + lr;
                pfr[mt] = *(const bf16x8*)(smem + prow * 256 + ((64 * kc + 16 * g) ^ ((prow & 7) << 4)));
            }
#pragma unroll
            for (int nt4 = 0; nt4 < 4; nt4++) {
                bf16x8 vfr = *(const bf16x8*)(vB + ((size_t)((s * 4 + nt4) * 8 + 4 * t + kc) << 9) + (l << 3));
                oacc[0][nt4] = MFMA_B16(pfr[0], vfr, oacc[0][nt4]);
                oacc[1][nt4] = MFMA_B16(pfr[1], vfr, oacc[1][nt4]);
            }
        }
        LGKM0();
    }

    // ============ out-proj: O bounce -> O@Wro; keep x_new in registers ======
#pragma unroll
    for (int mt = 0; mt < 2; mt++)
#pragma unroll
        for (int i = 0; i < 4; i++) {
            float rl = 1.0f / l_run[mt][i];
            int row = 4 * g + i + 16 * mt;
            int swo = (row & 7) << 4;
#pragma unroll
            for (int nt = 0; nt < 4; nt++) {
                int col = lr + 16 * nt;
                *(ushort*)(smem + row * 128 + ((2 * col) ^ swo)) = f2bf(oacc[mt][nt][i] * rl);
            }
        }
    LGKM0();
    bf16x8 ofr[2][2];
#pragma unroll
    for (int mt = 0; mt < 2; mt++)
#pragma unroll
        for (int kf2 = 0; kf2 < 2; kf2++) {
            int row = 16 * mt + lr;
            int rd = row * 128 + ((64 * kf2 + 16 * g) ^ ((row & 7) << 4));
            ofr[mt][kf2] = *(const bf16x8*)(smem + rd);
        }

    f32x4 xn[2][8];   // x after attention: rows 32qc+16mt+4g+i, cols lr+16nt
#pragma unroll
    for (int nt = 0; nt < 8; nt++) {
        f32x4 acc2[2];
        acc2[0] = (f32x4){0.f, 0.f, 0.f, 0.f};
        acc2[1] = (f32x4){0.f, 0.f, 0.f, 0.f};
#pragma unroll
        for (int kf2 = 0; kf2 < 2; kf2++) {
            bf16x8 wfr = *(const bf16x8*)(wroF + (((nt << 1) | kf2) << 9) + (l << 3));
            acc2[0] = MFMA_B16(ofr[0][kf2], wfr, acc2[0]);
            acc2[1] = MFMA_B16(ofr[1][kf2], wfr, acc2[1]);
        }
        int col = lr + 16 * nt;
        float brod = bro[col];
#pragma unroll
        for (int mt = 0; mt < 2; mt++)
#pragma unroll
            for (int i = 0; i < 4; i++) {
                int row = 32 * qc + 16 * mt + 4 * g + i;
                size_t off = (size_t)s * 32768 + (size_t)row * 128 + col;
                xn[mt][nt][i] = x[off] + acc2[mt][i] + brod;
            }
    }

    // ============ MLP LN (16-lane-group reduce) -> yn into region0 ==========
    {
        float glc[8], elc[8];
#pragma unroll
        for (int nt = 0; nt < 8; nt++) { glc[nt] = mn_g[lr + 16 * nt]; elc[nt] = mn_b[lr + 16 * nt]; }
#pragma unroll
        for (int mt = 0; mt < 2; mt++)
#pragma unroll
            for (int i = 0; i < 4; i++) {
                float sS = 0.f, qS = 0.f;
#pragma unroll
                for (int nt = 0; nt < 8; nt++) { float v = xn[mt][nt][i]; sS += v; qS += v * v; }
#pragma unroll
                for (int off = 1; off < 16; off <<= 1) { sS += __shfl_xor(sS, off); qS += __shfl_xor(qS, off); }
                float mu = sS * (1.0f / 128.0f);
                float var = qS * (1.0f / 128.0f) - mu * mu;
                float rs = rsqrtf(var + 1e-5f);
                int row = 16 * mt + 4 * g + i;
                int sw = (row & 7) << 4;
#pragma unroll
                for (int nt = 0; nt < 8; nt++) {
                    int col = lr + 16 * nt;
                    *(ushort*)(smem + row * 256 + ((2 * col) ^ sw)) =
                        f2bf((xn[mt][nt][i] - mu) * rs * glc[nt] + elc[nt]);
                }
            }
    }
    LGKM0();

    bf16x8 afrm[2][4];
#pragma unroll
    for (int mt = 0; mt < 2; mt++)
#pragma unroll
        for (int kf = 0; kf < 4; kf++) {
            int row = 16 * mt + lr;
            afrm[mt][kf] = *(const bf16x8*)(smem + row * 256 + ((16 * g + 64 * kf) ^ ((row & 7) << 4)));
        }

    // ============ MLP GEMM (v6 structure, B-frags shared across mt) =========
    f32x4 mo[2][8];
#pragma unroll
    for (int mt = 0; mt < 2; mt++)
#pragma unroll
        for (int nt = 0; nt < 8; nt++) mo[mt][nt] = (f32x4){0.f, 0.f, 0.f, 0.f};

    unsigned char* hsc = smem + 8192;   // region1 [32 rows][64B], swz (row&3)<<4
#pragma unroll
    for (int kb = 0; kb < 2; kb++) {
#pragma unroll
        for (int cc = 0; cc < 4; cc++) {
#pragma unroll
            for (int nt2 = 0; nt2 < 2; nt2++) {
                int nt = 2 * cc + nt2;
                f32x4 a1[2];
                a1[0] = (f32x4){0.f, 0.f, 0.f, 0.f};
                a1[1] = (f32x4){0.f, 0.f, 0.f, 0.f};
#pragma unroll
                for (int kf = 0; kf < 4; kf++) {
                    bf16x8 bfr = *(const bf16x8*)(w1F + (((((kb << 3) | nt) << 2) | kf) << 9) + (l << 3));
                    a1[0] = MFMA_B16(afrm[0][kf], bfr, a1[0]);
                    a1[1] = MFMA_B16(afrm[1][kf], bfr, a1[1]);
                }
                float bb1 = b1[128 * kb + 16 * nt + lr];
                int colc = lr + 16 * nt2;   // 0..31 within chunk
#pragma unroll
                for (int mt = 0; mt < 2; mt++)
#pragma unroll
                    for (int i = 0; i < 4; i++) {
                        int row = 16 * mt + 4 * g + i;
                        int ad = row * 64 + ((2 * colc) ^ ((row & 3) << 4));
                        *(ushort*)(hsc + ad) = f2bf(fmaxf(a1[mt][i] + bb1, 0.f));
                    }
            }
            LGKM0();

            bf16x8 hfr[2];
#pragma unroll
            for (int mt = 0; mt < 2; mt++) {
                int row = 16 * mt + lr;
                hfr[mt] = *(const bf16x8*)(hsc + row * 64 + ((16 * g) ^ ((row & 3) << 4)));
            }
#pragma unroll
            for (int nt = 0; nt < 8; nt++) {
                bf16x8 bfr = *(const bf16x8*)(w2F + (((((kb << 3) | nt) << 2) | cc) << 9) + (l << 3));
                mo[0][nt] = MFMA_B16(hfr[0], bfr, mo[0][nt]);
                mo[1][nt] = MFMA_B16(hfr[1], bfr, mo[1][nt]);
            }
            LGKM0();   // hsc reads done before next chunk overwrites
        }
    }

    // ============ final write: out = x_new + mlp_delta + b2 =================
#pragma unroll
    for (int nt = 0; nt < 8; nt++) {
        int col = lr + 16 * nt;
        float b2c = b2[col];
#pragma unroll
        for (int mt = 0; mt < 2; mt++)
#pragma unroll
            for (int i = 0; i < 4; i++) {
                int row = 32 * qc + 16 * mt + 4 * g + i;
                size_t off = (size_t)s * 32768 + (size_t)row * 128 + col;
                x[off] = xn[mt][nt][i] + mo[mt][nt][i] + b2c;
            }
    }
}

// ---------------------------------------------------------------------------
// E (fused MFMA attention) — FALLBACK when ws is too small for the split path.
// ---------------------------------------------------------------------------
__global__ __launch_bounds__(512, 2) void k_attn_mfma(
    float* __restrict__ x,
    const float* __restrict__ rn_g, const float* __restrict__ rn_b,
    const ushort* __restrict__ wqF, const ushort* __restrict__ wkF,
    const ushort* __restrict__ wvF, const float* __restrict__ brv,
    const float* __restrict__ Wro, const float* __restrict__ bro)
{
    __shared__ __align__(16) unsigned char smem[131072];

    int tid = threadIdx.x;
    int w  = tid >> 6;
    int l  = tid & 63;
    int g  = l >> 4;
    int lr = l & 15;
    size_t base = (size_t)blockIdx.x * 32768;

    float gl0 = rn_g[l], gl1 = rn_g[l + 64];
    float el0 = rn_b[l], el1 = rn_b[l + 64];

    for (int h = 0; h < 2; h++) {
        for (int rr = 0; rr < 16; rr++) {
            int rloc = 16 * w + rr;
            size_t ro = base + (size_t)(128 * h + rloc) * 128;
            float x0 = x[ro + l], x1 = x[ro + l + 64];
            float s = x0 + x1, q = x0 * x0 + x1 * x1;
#pragma unroll
            for (int off = 32; off; off >>= 1) { s += __shfl_xor(s, off); q += __shfl_xor(q, off); }
            float mu = s * (1.0f / 128.0f);
            float var = q * (1.0f / 128.0f) - mu * mu;
            float rs = rsqrtf(var + 1e-5f);
            int sw = (rloc & 7) << 4;
            *(ushort*)(smem + 65536 + rloc * 256 + ((2 * l) ^ sw))        = f2bf((x0 - mu) * rs * gl0 + el0);
            *(ushort*)(smem + 65536 + rloc * 256 + ((2 * (l + 64)) ^ sw)) = f2bf((x1 - mu) * rs * gl1 + el1);
        }
        LGKM0();

        bf16x8 afr[4];
        int arow = 16 * w + lr;
#pragma unroll
        for (int kf = 0; kf < 4; kf++) {
            int ab = 65536 + arow * 256 + ((16 * g + 64 * kf) ^ ((arow & 7) << 4));
            afr[kf] = *(const bf16x8*)(smem + ab);
        }
#pragma unroll
        for (int m = 0; m < 3; m++) {
            const ushort* wT = (m == 0) ? wqF : (m == 1) ? wkF : wvF;
            f32x4 acc[4];
#pragma unroll
            for (int nt = 0; nt < 4; nt++) acc[nt] = (f32x4){0.f, 0.f, 0.f, 0.f};
#pragma unroll
            for (int kf = 0; kf < 4; kf++) {
#pragma unroll
                for (int nt = 0; nt < 4; nt++) {
                    bf16x8 bfr = *(const bf16x8*)(wT + (((nt << 2) | kf) << 9) + (l << 3));
                    acc[nt] = MFMA_B16(afr[kf], bfr, acc[nt]);
                }
            }
#pragma unroll
            for (int nt = 0; nt < 4; nt++) {
                int col = lr + 16 * nt;
                float bv = (m == 2) ? brv[col] : 0.f;
#pragma unroll
                for (int i = 0; i < 4; i++) {
                    int qrow = 128 * h + 16 * w + 4 * g + i;
                    float v = acc[nt][i];
                    if (m == 0) {
                        int ad = 98304 + qrow * 128 + ((2 * col) ^ ((qrow & 7) << 4));
                        *(ushort*)(smem + ad) = f2bf(v * 0.125f);
                    } else if (m == 1) {
                        int ad = qrow * 128 + ((2 * col) ^ ((qrow & 7) << 4));
                        *(ushort*)(smem + ad) = f2bf(v);
                    } else {
                        int ad = 32768 + col * 512 + ((2 * qrow) ^ ((col & 7) << 4));
                        *(ushort*)(smem + ad) = f2bf(v + bv);
                    }
                }
            }
        }
    }
    __syncthreads();

    bf16x8 qf[2][2];
#pragma unroll
    for (int mt = 0; mt < 2; mt++)
#pragma unroll
        for (int kf = 0; kf < 2; kf++) {
            int qrow = 32 * w + 16 * mt + lr;
            int ab = 98304 + qrow * 128 + ((16 * g + 64 * kf) ^ ((qrow & 7) << 4));
            qf[mt][kf] = *(const bf16x8*)(smem + ab);
        }
    __syncthreads();

    float m_run[2][4], l_run[2][4];
    f32x4 oacc[2][4];
#pragma unroll
    for (int mt = 0; mt < 2; mt++)
#pragma unroll
        for (int i = 0; i < 4; i++) { m_run[mt][i] = -INFINITY; l_run[mt][i] = 0.f; }
#pragma unroll
    for (int mt = 0; mt < 2; mt++)
#pragma unroll
        for (int nt = 0; nt < 4; nt++) oacc[mt][nt] = (f32x4){0.f, 0.f, 0.f, 0.f};

    for (int t = 0; t < 2; t++) {
        f32x4 sacc[2][8];
#pragma unroll
        for (int mt = 0; mt < 2; mt++)
#pragma unroll
            for (int nt = 0; nt < 8; nt++) sacc[mt][nt] = (f32x4){0.f, 0.f, 0.f, 0.f};
#pragma unroll
        for (int nt = 0; nt < 8; nt++) {
#pragma unroll
            for (int kf = 0; kf < 2; kf++) {
                int key = 128 * t + 16 * nt + lr;
                int ab = key * 128 + ((16 * g + 64 * kf) ^ ((key & 7) << 4));
                bf16x8 bfr = *(const bf16x8*)(smem + ab);
#pragma unroll
                for (int mt = 0; mt < 2; mt++)
                    sacc[mt][nt] = MFMA_B16(qf[mt][kf], bfr, sacc[mt][nt]);
            }
        }
#pragma unroll
        for (int mt = 0; mt < 2; mt++) {
#pragma unroll
            for (int i = 0; i < 4; i++) {
                float mx = sacc[mt][0][i];
#pragma unroll
                for (int nt = 1; nt < 8; nt++) mx = fmaxf(mx, sacc[mt][nt][i]);
#pragma unroll
                for (int off = 1; off < 16; off <<= 1) mx = fmaxf(mx, __shfl_xor(mx, off));
                float mnew = fmaxf(m_run[mt][i], mx);
                float corr = __expf(m_run[mt][i] - mnew);
                m_run[mt][i] = mnew;
                int qrow = 32 * w + 16 * mt + 4 * g + i;
                int swq = (qrow & 7) << 4;
                float rs = 0.f;
#pragma unroll
                for (int nt = 0; nt < 8; nt++) {
                    float p = __expf(sacc[mt][nt][i] - mnew);
                    rs += p;
                    int col = lr + 16 * nt;
                    *(ushort*)(smem + 65536 + qrow * 256 + ((2 * col) ^ swq)) = f2bf(p);
                }
#pragma unroll
                for (int off = 1; off < 16; off <<= 1) rs += __shfl_xor(rs, off);
                l_run[mt][i] = l_run[mt][i] * corr + rs;
#pragma unroll
                for (int nt = 0; nt < 4; nt++) oacc[mt][nt][i] *= corr;
            }
        }
        LGKM0();

#pragma unroll
        for (int kf = 0; kf < 4; kf++) {
            bf16x8 pfr[2];
#pragma unroll
            for (int mt = 0; mt < 2; mt++) {
                int qrow = 32 * w + 16 * mt + lr;
                int ab = 65536 + qrow * 256 + ((16 * g + 64 * kf) ^ ((qrow & 7) << 4));
                pfr[mt] = *(const bf16x8*)(smem + ab);
            }
#pragma unroll
            for (int nt = 0; nt < 4; nt++) {
                int d = lr + 16 * nt;
                int bb = 32768 + d * 512 + ((16 * g + 64 * kf + 256 * t) ^ ((d & 7) << 4));
                bf16x8 bfr = *(const bf16x8*)(smem + bb);
#pragma unroll
                for (int mt = 0; mt < 2; mt++)
                    oacc[mt][nt] = MFMA_B16(pfr[mt], bfr, oacc[mt][nt]);
            }
        }
    }
    __syncthreads();

#pragma unroll
    for (int mt = 0; mt < 2; mt++)
#pragma unroll
        for (int i = 0; i < 4; i++) {
            float rl = 1.0f / l_run[mt][i];
            int qrow = 32 * w + 16 * mt + 4 * g + i;
            int swq = (qrow & 7) << 4;
#pragma unroll
            for (int nt = 0; nt < 4; nt++) {
                int col = lr + 16 * nt;
                *(ushort*)(smem + 65536 + qrow * 128 + ((2 * col) ^ swq)) = f2bf(oacc[mt][nt][i] * rl);
            }
        }
    for (int e = tid; e < 8192; e += 512) {
        int k = e >> 7, c = e & 127;
        int ad = c * 128 + ((2 * k) ^ ((c & 7) << 4));
        *(ushort*)(smem + ad) = f2bf(Wro[e]);
    }
    __syncthreads();

#pragma unroll
    for (int mt = 0; mt < 2; mt++) {
        bf16x8 ofr[2];
#pragma unroll
        for (int kf = 0; kf < 2; kf++) {
            int orow = 32 * w + 16 * mt + lr;
            int ab = 65536 + orow * 128 + ((16 * g + 64 * kf) ^ ((orow & 7) << 4));
            ofr[kf] = *(const bf16x8*)(smem + ab);
        }
#pragma unroll
        for (int nt = 0; nt < 8; nt++) {
            f32x4 acc = (f32x4){0.f, 0.f, 0.f, 0.f};
#pragma unroll
            for (int kf = 0; kf < 2; kf++) {
                int c = lr + 16 * nt;
                int bb = c * 128 + ((16 * g + 64 * kf) ^ ((c & 7) << 4));
                bf16x8 bfr = *(const bf16x8*)(smem + bb);
                acc = MFMA_B16(ofr[kf], bfr, acc);
            }
            int col = lr + 16 * nt;
            float brod = bro[col];
#pragma unroll
            for (int i = 0; i < 4; i++) {
                int qrow = 32 * w + 16 * mt + 4 * g + i;
                size_t off = base + (size_t)qrow * 128 + col;
                x[off] = x[off] + acc[i] + brod;
            }
        }
    }
}

// ---------------------------------------------------------------------------
// F (MFMA MLP v6) — FALLBACK path only (split path fuses MLP into k_attn_mlp).
// ---------------------------------------------------------------------------
__global__ __launch_bounds__(64, 4) void k_mlp_mfma(
    float* __restrict__ x,
    const float* __restrict__ mn_g, const float* __restrict__ mn_b,
    const ushort* __restrict__ w1F, const ushort* __restrict__ w2F,
    const float* __restrict__ b1, const float* __restrict__ b2)
{
    __shared__ __align__(16) unsigned char smem[5120];
    int l = threadIdx.x;
    int g = l >> 4, lr = l & 15;
    size_t rbase = (size_t)blockIdx.x * 16;

    {
        float gl0 = mn_g[l], gl1 = mn_g[l + 64];
        float el0 = mn_b[l], el1 = mn_b[l + 64];
#pragma unroll
        for (int bb = 0; bb < 4; bb++) {
            float a0[4], a1[4];
#pragma unroll
            for (int rr = 0; rr < 4; rr++) {
                size_t ro = (rbase + 4 * bb + rr) * 128;
                a0[rr] = x[ro + l];
                a1[rr] = x[ro + l + 64];
            }
#pragma unroll
            for (int rr = 0; rr < 4; rr++) {
                int rloc = 4 * bb + rr;
                float x0 = a0[rr], x1 = a1[rr];
                float s = x0 + x1, q = x0 * x0 + x1 * x1;
#pragma unroll
                for (int off = 32; off; off >>= 1) { s += __shfl_xor(s, off); q += __shfl_xor(q, off); }
                float mu = s * (1.0f / 128.0f);
                float var = q * (1.0f / 128.0f) - mu * mu;
                float rs = rsqrtf(var + 1e-5f);
                int sw = (rloc & 7) << 4;
                *(ushort*)(smem + rloc * 256 + ((2 * l) ^ sw))        = f2bf((x0 - mu) * rs * gl0 + el0);
                *(ushort*)(smem + rloc * 256 + ((2 * (l + 64)) ^ sw)) = f2bf((x1 - mu) * rs * gl1 + el1);
            }
        }
    }
    LGKM0();

    bf16x8 afr[4];
#pragma unroll
    for (int kf = 0; kf < 4; kf++) {
        afr[kf] = *(const bf16x8*)(smem + lr * 256 + ((16 * g + 64 * kf) ^ ((lr & 7) << 4)));
    }

    f32x4 oacc[8];
#pragma unroll
    for (int nt = 0; nt < 8; nt++) oacc[nt] = (f32x4){0.f, 0.f, 0.f, 0.f};

#pragma unroll
    for (int kb = 0; kb < 2; kb++) {
#pragma unroll
        for (int cc = 0; cc < 4; cc++) {
#pragma unroll
            for (int nt2 = 0; nt2 < 2; nt2++) {
                int nt = 2 * cc + nt2;
                f32x4 acc = (f32x4){0.f, 0.f, 0.f, 0.f};
#pragma unroll
                for (int kf = 0; kf < 4; kf++) {
                    bf16x8 bfr = *(const bf16x8*)(w1F + (((((kb << 3) | nt) << 2) | kf) << 9) + (l << 3));
                    acc = MFMA_B16(afr[kf], bfr, acc);
                }
                float bb1 = b1[128 * kb + 16 * nt + lr];
                int colc = lr + 16 * nt2;
#pragma unroll
                for (int i = 0; i < 4; i++) {
                    int row = 4 * g + i;
                    int ad = 4096 + row * 64 + ((2 * colc) ^ ((row & 3) << 4));
                    *(ushort*)(smem + ad) = f2bf(fmaxf(acc[i] + bb1, 0.f));
                }
            }
            LGKM0();

            bf16x8 hfr = *(const bf16x8*)(smem + 4096 + lr * 64 + ((16 * g) ^ ((lr & 3) << 4)));
#pragma unroll
            for (int nt = 0; nt < 8; nt++) {
                bf16x8 bfr = *(const bf16x8*)(w2F + (((((kb << 3) | nt) << 2) | cc) << 9) + (l << 3));
                oacc[nt] = MFMA_B16(hfr, bfr, oacc[nt]);
            }
            LGKM0();
        }
    }

#pragma unroll
    for (int nt = 0; nt < 8; nt++) {
        int col = 16 * nt + lr;
#pragma unroll
        for (int i = 0; i < 4; i++) {
            int row = 4 * g + i;
            int ad = row * 256 + ((2 * col) ^ ((row & 7) << 4));
            *(ushort*)(smem + ad) = f2bf(oacc[nt][i]);
        }
    }
    LGKM0();
    {
        float b20 = b2[l], b21 = b2[l + 64];
#pragma unroll
        for (int rr = 0; rr < 16; rr++) {
            int sw = (rr & 7) << 4;
            float d0 = lbf(*(const ushort*)(smem + rr * 256 + ((2 * l) ^ sw)));
            float d1 = lbf(*(const ushort*)(smem + rr * 256 + ((2 * (l + 64)) ^ sw)));
            size_t ro = (rbase + rr) * 128;
            x[ro + l]      = x[ro + l]      + d0 + b20;
            x[ro + l + 64] = x[ro + l + 64] + d1 + b21;
        }
    }
}

// ---------------------------------------------------------------------------
extern "C" void kernel_launch(void* const* d_in, const int* in_sizes, int n_in,
                              void* d_out, int out_size, void* d_ws, size_t ws_size,
                              hipStream_t stream)
{
    const float* seq   = (const float*)d_in[0];
    const float* pair  = (const float*)d_in[1];
    const float* sn_g  = (const float*)d_in[2];
    const float* sn_b  = (const float*)d_in[3];
    const float* Wq    = (const float*)d_in[4];
    const float* Wk    = (const float*)d_in[5];
    const float* Wyq   = (const float*)d_in[6];
    const float* Wyk   = (const float*)d_in[7];
    const float* Wdist = (const float*)d_in[8];
    const float* Wout  = (const float*)d_in[9];
    const float* bout  = (const float*)d_in[10];
    const float* rn_g  = (const float*)d_in[11];
    const float* rn_b  = (const float*)d_in[12];
    const float* Wrq   = (const float*)d_in[13];
    const float* Wrk   = (const float*)d_in[14];
    const float* Wrv   = (const float*)d_in[15];
    const float* brv   = (const float*)d_in[16];
    const float* Wro   = (const float*)d_in[17];
    const float* bro   = (const float*)d_in[18];
    const float* mn_g  = (const float*)d_in[19];
    const float* mn_b  = (const float*)d_in[20];
    const float* W1    = (const float*)d_in[21];
    const float* b1    = (const float*)d_in[22];
    const float* W2    = (const float*)d_in[23];
    const float* b2    = (const float*)d_in[24];
    (void)in_sizes; (void)n_in; (void)out_size;

    float*  x2   = (float*)d_ws;           // 262144 f32
    float*  a2   = x2 + 262144;            // 65536
    float*  c2   = a2 + 65536;             // 65536
    float*  wd2  = c2 + 65536;             // 512
    ushort* wqF  = (ushort*)(wd2 + 512);   // 8192 each
    ushort* wkF  = wqF + 8192;
    ushort* wvF  = wkF + 8192;
    ushort* wroF = wvF + 8192;             // 8192
    ushort* w1F  = wroF + 8192;            // 32768
    ushort* w2F  = w1F + 32768;            // 32768
    ushort* qA   = w2F + 32768;            // 8388608 each (split path only)
    ushort* kBp  = qA + 8388608;
    ushort* vBp  = kBp + 8388608;
    float*  xres = (float*)d_out;

    const size_t WS_NEED_SPLIT = 52103168ull;   // bytes incl. qA/kB/vB
    bool use_split = (ws_size >= WS_NEED_SPLIT);

    k_ln_pool  <<<512,   256, 0, stream>>>(seq, sn_g, sn_b, x2);
    k_proj     <<<512,   128, 0, stream>>>(x2, Wq, Wk, Wyq, Wyk, Wout, bout, a2, c2);
    k_wd2      <<<1,     128, 0, stream>>>(Wdist, Wout, wd2);
    k_wt       <<<64,    512, 0, stream>>>(Wrq, Wrk, Wrv, Wro, wqF, wkF, wvF, wroF);
    k_wt12     <<<128,   512, 0, stream>>>(W1, W2, w1F, w2F);
    if (use_split) {
        k_qkv_asm <<<4096, 64,  0, stream>>>(xres, pair, a2, c2, wd2,
                                             rn_g, rn_b, wqF, wkF, wvF, brv,
                                             qA, kBp, vBp);
        k_attn_mlp<<<2048, 128, 0, stream>>>(xres, qA, kBp, vBp, wroF, bro,
                                             mn_g, mn_b, w1F, w2F, b1, b2);
    } else {
        k_assemble <<<65536, 256, 0, stream>>>(pair, a2, c2, wd2, xres);
        k_attn_mfma<<<512,   512, 0, stream>>>(xres, rn_g, rn_b, wqF, wkF, wvF, brv, Wro, bro);
        k_mlp_mfma <<<8192,  64,  0, stream>>>(xres, mn_g, mn_b, w1F, w2F, b1, b2);
    }
}

// Round 23
// 210.650 us; speedup vs baseline: 1.3497x; 1.3497x over previous
//
#include <hip/hip_runtime.h>
#include <hip/hip_bf16.h>

using bf16 = __hip_bfloat16;
typedef unsigned int uint;
typedef unsigned short ushort;
typedef __attribute__((ext_vector_type(8))) short bf16x8;
typedef __attribute__((ext_vector_type(4))) float f32x4;

// Shapes: B=2, S=512, SD=512, P=256, PD=128, AD=64, H=256
// All global tensors are f32.
// This is the round-21 configuration (measured 209.4us), restored after the
// round-22 attn+MLP fusion spilled (allocator caps 128-thread kernels at 128
// VGPR regardless of launch_bounds; the fused working set needs ~230).

__device__ __forceinline__ float bfraw(uint u) { return __uint_as_float(u << 16); }
__device__ __forceinline__ ushort f2bf(float f) {
    bf16 h = __float2bfloat16(f);
    return *reinterpret_cast<ushort*>(&h);
}
__device__ __forceinline__ float lbf(ushort u) { return __uint_as_float(((uint)u) << 16); }

#define MFMA_B16(a, b, c) __builtin_amdgcn_mfma_f32_16x16x32_bf16((a), (b), (c), 0, 0, 0)
#define LGKM0() asm volatile("s_waitcnt lgkmcnt(0)" ::: "memory")

// ---------------------------------------------------------------------------
// A: LayerNorm(seq) over SD=512 + avg-pool row pairs -> x2 f32. 512 blocks.
// ---------------------------------------------------------------------------
__global__ __launch_bounds__(256) void k_ln_pool(
    const float* __restrict__ seq, const float* __restrict__ g,
    const float* __restrict__ be, float* __restrict__ x2)
{
    __shared__ float red[4][4];
    int bp = blockIdx.x;
    int t  = threadIdx.x;
    const float* r0 = seq + (size_t)(bp * 2) * 512;
    const float* r1 = r0 + 512;

    float a0 = r0[t], a1 = r0[t + 256];
    float c0 = r1[t], c1 = r1[t + 256];

    float s0 = a0 + a1, q0 = a0 * a0 + a1 * a1;
    float s1 = c0 + c1, q1 = c0 * c0 + c1 * c1;
#pragma unroll
    for (int off = 32; off; off >>= 1) {
        s0 += __shfl_xor(s0, off); q0 += __shfl_xor(q0, off);
        s1 += __shfl_xor(s1, off); q1 += __shfl_xor(q1, off);
    }
    int w = t >> 6, l = t & 63;
    if (l == 0) { red[0][w] = s0; red[1][w] = q0; red[2][w] = s1; red[3][w] = q1; }
    __syncthreads();
    s0 = red[0][0] + red[0][1] + red[0][2] + red[0][3];
    q0 = red[1][0] + red[1][1] + red[1][2] + red[1][3];
    s1 = red[2][0] + red[2][1] + red[2][2] + red[2][3];
    q1 = red[3][0] + red[3][1] + red[3][2] + red[3][3];

    const float inv = 1.0f / 512.0f;
    float mu0 = s0 * inv, var0 = q0 * inv - mu0 * mu0, rs0 = rsqrtf(var0 + 1e-5f);
    float mu1 = s1 * inv, var1 = q1 * inv - mu1 * mu1, rs1 = rsqrtf(var1 + 1e-5f);

    float g0 = g[t], g1 = g[t + 256];
    float e0 = be[t], e1 = be[t + 256];

    float o0 = 0.5f * ((a0 - mu0) * rs0 * g0 + e0 + (c0 - mu1) * rs1 * g0 + e0);
    float o1 = 0.5f * ((a1 - mu0) * rs0 * g1 + e1 + (c1 - mu1) * rs1 * g1 + e1);

    float* xo = x2 + (size_t)bp * 512;
    xo[t] = o0; xo[t + 256] = o1;
}

// ---------------------------------------------------------------------------
// B: A2 = (x@Wq + gelu(x)@Wyq)@Wout + bout ; C2 = (x@Wk + gelu(x)@Wyk)@Wout
// ---------------------------------------------------------------------------
__global__ __launch_bounds__(128) void k_proj(
    const float* __restrict__ x2,
    const float* __restrict__ Wq, const float* __restrict__ Wk,
    const float* __restrict__ Wyq, const float* __restrict__ Wyk,
    const float* __restrict__ Wout, const float* __restrict__ bout,
    float* __restrict__ a2, float* __restrict__ c2)
{
    __shared__ float xr[512], gxr[512], ar[128], cr[128];
    int row = blockIdx.x;
    int t   = threadIdx.x;

    for (int u = t; u < 512; u += 128) {
        float v = x2[(size_t)row * 512 + u];
        xr[u]  = v;
        gxr[u] = 0.5f * v * (1.0f + erff(v * 0.70710678118654752f));
    }
    __syncthreads();

    float a = 0.f, c = 0.f;
    for (int s = 0; s < 512; s++) {
        float xs = xr[s], gs = gxr[s];
        a += xs * Wq[s * 128 + t] + gs * Wyq[s * 128 + t];
        c += xs * Wk[s * 128 + t] + gs * Wyk[s * 128 + t];
    }
    ar[t] = a; cr[t] = c;
    __syncthreads();

    float A = bout[t], C = 0.f;
    for (int u = 0; u < 128; u++) {
        float wv = Wout[u * 128 + t];
        A += ar[u] * wv;
        C += cr[u] * wv;
    }
    a2[(size_t)row * 128 + t] = A;
    c2[(size_t)row * 128 + t] = C;
}

// ---------------------------------------------------------------------------
// W: Wd2 = Wdist(3x128) @ Wout(128x128)
// ---------------------------------------------------------------------------
__global__ __launch_bounds__(128) void k_wd2(
    const float* __restrict__ Wdist, const float* __restrict__ Wout,
    float* __restrict__ wd2)
{
    int t = threadIdx.x;
#pragma unroll
    for (int f = 0; f < 3; f++) {
        float acc = 0.f;
        for (int u = 0; u < 128; u++)
            acc += Wdist[f * 128 + u] * Wout[u * 128 + t];
        wd2[f * 128 + t] = acc;
    }
}

// ---------------------------------------------------------------------------
// WT prep (FRAGMENT-ORDER). m=0..2: Wrq/Wrk/Wrv; m=3: Wro.
// ---------------------------------------------------------------------------
__global__ __launch_bounds__(512) void k_wt(
    const float* __restrict__ Wrq, const float* __restrict__ Wrk,
    const float* __restrict__ Wrv, const float* __restrict__ Wro,
    ushort* __restrict__ wqF, ushort* __restrict__ wkF,
    ushort* __restrict__ wvF, ushort* __restrict__ wroF)
{
    int idx = blockIdx.x * 512 + threadIdx.x;       // 0 .. 4*8192
    int m = idx >> 13;
    int o = idx & 8191;
    int f = o >> 9;            // 0..15
    int l = (o >> 3) & 63;
    int j = o & 7;
    if (m < 3) {
        int nt = f >> 2, kf = f & 3;
        const float* W = (m == 0) ? Wrq : (m == 1) ? Wrk : Wrv;
        ushort* T = (m == 0) ? wqF : (m == 1) ? wkF : wvF;
        T[o] = f2bf(W[(32 * kf + 8 * (l >> 4) + j) * 64 + 16 * nt + (l & 15)]);
    } else {
        int nt = f >> 1, kf2 = f & 1;
        wroF[o] = f2bf(Wro[(32 * kf2 + 8 * (l >> 4) + j) * 128 + 16 * nt + (l & 15)]);
    }
}

// ---------------------------------------------------------------------------
// WT prep 2 (MLP, FRAGMENT-ORDER)
// ---------------------------------------------------------------------------
__global__ __launch_bounds__(512) void k_wt12(
    const float* __restrict__ W1, const float* __restrict__ W2,
    ushort* __restrict__ w1F, ushort* __restrict__ w2F)
{
    int idx = blockIdx.x * 512 + threadIdx.x;   // 0 .. 65536
    int o = idx & 32767;
    int f = o >> 9;            // 0..63
    int l = (o >> 3) & 63;
    int j = o & 7;
    int kb = f >> 5, nt = (f >> 2) & 7, kf = f & 3;
    if (idx < 32768) {
        int R = 128 * kb + 16 * nt + (l & 15);
        int C = 32 * kf + 8 * (l >> 4) + j;
        w1F[o] = f2bf(W1[C * 256 + R]);
    } else {
        int R2 = 16 * nt + (l & 15);
        int C2 = 128 * kb + 32 * kf + 8 * (l >> 4) + j;
        w2F[o] = f2bf(W2[C2 * 128 + R2]);
    }
}

// ---------------------------------------------------------------------------
// C: assemble (FALLBACK path only)
// ---------------------------------------------------------------------------
__global__ __launch_bounds__(256) void k_assemble(
    const float* __restrict__ pair, const float* __restrict__ a2,
    const float* __restrict__ c2, const float* __restrict__ wd2,
    float* __restrict__ xout)
{
    size_t idx = (size_t)blockIdx.x * 256 + threadIdx.x;
    int d = (int)(idx & 127);
    size_t r = idx >> 7;
    int j = (int)(r & 255); r >>= 8;
    int i = (int)(r & 255);
    int b = (int)(r >> 8);

    float ds = fabsf((float)(i - j)) * (1.0f / 255.0f);
    float sg = (float)((i > j) - (i < j));
    float ex = __expf(-ds);

    float v = pair[idx]
            + a2[(size_t)(b * 256 + i) * 128 + d]
            + c2[(size_t)(b * 256 + j) * 128 + d]
            + ds * wd2[d] + sg * wd2[128 + d] + ex * wd2[256 + d];
    xout[idx] = v;
}

// ---------------------------------------------------------------------------
// QKV + ASSEMBLE (split path, fused; proven round 21).
// ---------------------------------------------------------------------------
__global__ __launch_bounds__(64, 2) void k_qkv_asm(
    float* __restrict__ x, const float* __restrict__ pair,
    const float* __restrict__ a2, const float* __restrict__ c2,
    const float* __restrict__ wd2,
    const float* __restrict__ rn_g, const float* __restrict__ rn_b,
    const ushort* __restrict__ wqF, const ushort* __restrict__ wkF,
    const ushort* __restrict__ wvF, const float* __restrict__ brv,
    ushort* __restrict__ qA, ushort* __restrict__ kB, ushort* __restrict__ vB)
{
    __shared__ __align__(16) unsigned char smem[12288];
    int l = threadIdx.x;
    int g = l >> 4, lr = l & 15;
    int s = blockIdx.x & 511;
    int c = blockIdx.x >> 9;
    size_t xbase = (size_t)s * 32768 + (size_t)(32 * c) * 128;

    {
        float gl0 = rn_g[l], gl1 = rn_g[l + 64];
        float el0 = rn_b[l], el1 = rn_b[l + 64];
        int b  = s >> 8;
        int ii = s & 255;
        float a20 = a2[(size_t)s * 128 + l];
        float a21 = a2[(size_t)s * 128 + l + 64];
        float wdA0 = wd2[l],       wdA1 = wd2[l + 64];
        float wdB0 = wd2[128 + l], wdB1 = wd2[128 + l + 64];
        float wdC0 = wd2[256 + l], wdC1 = wd2[256 + l + 64];
#pragma unroll
        for (int bb = 0; bb < 8; bb++) {
            float p0[4], p1[4], c20[4], c21[4];
#pragma unroll
            for (int rr = 0; rr < 4; rr++) {
                size_t ro = xbase + (size_t)(4 * bb + rr) * 128;
                p0[rr] = pair[ro + l]; p1[rr] = pair[ro + l + 64];
                int j = 32 * c + 4 * bb + rr;
                c20[rr] = c2[(size_t)(b * 256 + j) * 128 + l];
                c21[rr] = c2[(size_t)(b * 256 + j) * 128 + l + 64];
            }
#pragma unroll
            for (int rr = 0; rr < 4; rr++) {
                int rloc = 4 * bb + rr;
                int j = 32 * c + rloc;
                float dsv = fabsf((float)(ii - j)) * (1.0f / 255.0f);
                float sgv = (float)((ii > j) - (ii < j));
                float exv = __expf(-dsv);
                float x0 = p0[rr] + a20 + c20[rr] + dsv * wdA0 + sgv * wdB0 + exv * wdC0;
                float x1 = p1[rr] + a21 + c21[rr] + dsv * wdA1 + sgv * wdB1 + exv * wdC1;
                size_t ro = xbase + (size_t)rloc * 128;
                x[ro + l] = x0; x[ro + l + 64] = x1;
                float sS = x0 + x1, qS = x0 * x0 + x1 * x1;
#pragma unroll
                for (int off = 32; off; off >>= 1) { sS += __shfl_xor(sS, off); qS += __shfl_xor(qS, off); }
                float mu = sS * (1.0f / 128.0f);
                float var = qS * (1.0f / 128.0f) - mu * mu;
                float rs = rsqrtf(var + 1e-5f);
                int sw = (rloc & 7) << 4;
                *(ushort*)(smem + rloc * 256 + ((2 * l) ^ sw))        = f2bf((x0 - mu) * rs * gl0 + el0);
                *(ushort*)(smem + rloc * 256 + ((2 * (l + 64)) ^ sw)) = f2bf((x1 - mu) * rs * gl1 + el1);
            }
        }
    }
    LGKM0();

    bf16x8 afr[2][4];
#pragma unroll
    for (int mt = 0; mt < 2; mt++)
#pragma unroll
        for (int kf = 0; kf < 4; kf++) {
            int row = 16 * mt + lr;
            afr[mt][kf] = *(const bf16x8*)(smem + row * 256 + ((16 * g + 64 * kf) ^ ((row & 7) << 4)));
        }

    unsigned char* dscr = smem + 8192;

#pragma unroll
    for (int mqk = 0; mqk < 2; mqk++) {
        const ushort* wF = mqk ? wkF : wqF;
        ushort* dst = mqk ? kB : qA;
        float scale = mqk ? 1.0f : 0.125f;
#pragma unroll
        for (int mt = 0; mt < 2; mt++) {
#pragma unroll
            for (int nt = 0; nt < 4; nt++) {
                f32x4 acc = (f32x4){0.f, 0.f, 0.f, 0.f};
#pragma unroll
                for (int kf = 0; kf < 4; kf++) {
                    bf16x8 bfr = *(const bf16x8*)(wF + (((nt << 2) | kf) << 9) + (l << 3));
                    acc = MFMA_B16(afr[mt][kf], bfr, acc);
                }
                int col = lr + 16 * nt;
#pragma unroll
                for (int i = 0; i < 4; i++) {
                    int row = 4 * g + i + 16 * mt;
                    int ad = row * 128 + ((2 * col) ^ ((row & 7) << 4));
                    *(ushort*)(dscr + ad) = f2bf(acc[i] * scale);
                }
            }
        }
        LGKM0();
#pragma unroll
        for (int mt = 0; mt < 2; mt++)
#pragma unroll
            for (int kf2 = 0; kf2 < 2; kf2++) {
                int row = 16 * mt + lr;
                int rd = row * 128 + ((64 * kf2 + 16 * g) ^ ((row & 7) << 4));
                bf16x8 v = *(const bf16x8*)(dscr + rd);
                *(bf16x8*)(dst + ((size_t)((s * 16 + 2 * c + mt) * 2 + kf2) << 9) + (l << 3)) = v;
            }
        LGKM0();
    }

#pragma unroll
    for (int mt = 0; mt < 2; mt++) {
#pragma unroll
        for (int nt = 0; nt < 4; nt++) {
            f32x4 acc = (f32x4){0.f, 0.f, 0.f, 0.f};
#pragma unroll
            for (int kf = 0; kf < 4; kf++) {
                bf16x8 bfr = *(const bf16x8*)(wvF + (((nt << 2) | kf) << 9) + (l << 3));
                acc = MFMA_B16(afr[mt][kf], bfr, acc);
            }
            int d = lr + 16 * nt;
            float bv = brv[d];
#pragma unroll
            for (int i = 0; i < 4; i++) {
                int kk = 4 * g + i + 16 * mt;
                int ad = d * 64 + ((2 * kk) ^ ((d & 3) << 4));
                *(ushort*)(dscr + ad) = f2bf(acc[i] + bv);
            }
        }
    }
    LGKM0();
#pragma unroll
    for (int nt2 = 0; nt2 < 4; nt2++) {
        int d = 16 * nt2 + lr;
        int rd = d * 64 + ((16 * g) ^ ((d & 3) << 4));
        bf16x8 vv = *(const bf16x8*)(dscr + rd);
        *(bf16x8*)(vB + ((size_t)((s * 4 + nt2) * 8 + c) << 9) + (l << 3)) = vv;
    }
}

// ---------------------------------------------------------------------------
// Flash + out-proj (split path; proven rounds 18/20/21).
// ---------------------------------------------------------------------------
__global__ __launch_bounds__(128, 2) void k_attn2(
    float* __restrict__ x,
    const ushort* __restrict__ qA, const ushort* __restrict__ kB,
    const ushort* __restrict__ vB, const ushort* __restrict__ wroF,
    const float* __restrict__ bro)
{
    __shared__ __align__(16) unsigned char smem_all[16384];
    int tid = threadIdx.x;
    int w = tid >> 6;
    int l = tid & 63, g = l >> 4, lr = l & 15;
    int s = blockIdx.x & 511;               // slice (XCD-locality)
    int qc = ((blockIdx.x >> 9) << 1) | w;  // q-chunk 0..7
    unsigned char* smem = smem_all + (w << 13);   // private 8KB per wave

    bf16x8 qf[2][2];
#pragma unroll
    for (int mt = 0; mt < 2; mt++)
#pragma unroll
        for (int kf2 = 0; kf2 < 2; kf2++)
            qf[mt][kf2] = *(const bf16x8*)(qA + ((size_t)((s * 16 + 2 * qc + mt) * 2 + kf2) << 9) + (l << 3));

    float m_run[2][4], l_run[2][4];
    f32x4 oacc[2][4];
#pragma unroll
    for (int mt = 0; mt < 2; mt++)
#pragma unroll
        for (int i = 0; i < 4; i++) { m_run[mt][i] = -INFINITY; l_run[mt][i] = 0.f; }
#pragma unroll
    for (int mt = 0; mt < 2; mt++)
#pragma unroll
        for (int nt = 0; nt < 4; nt++) oacc[mt][nt] = (f32x4){0.f, 0.f, 0.f, 0.f};

    for (int t = 0; t < 2; t++) {
        f32x4 sacc[2][8];
#pragma unroll
        for (int mt = 0; mt < 2; mt++)
#pragma unroll
            for (int nt = 0; nt < 8; nt++) sacc[mt][nt] = (f32x4){0.f, 0.f, 0.f, 0.f};
#pragma unroll
        for (int nt = 0; nt < 8; nt++) {
            int kt = 8 * t + nt;
#pragma unroll
            for (int kf2 = 0; kf2 < 2; kf2++) {
                bf16x8 kfr = *(const bf16x8*)(kB + ((size_t)((s * 16 + kt) * 2 + kf2) << 9) + (l << 3));
                sacc[0][nt] = MFMA_B16(qf[0][kf2], kfr, sacc[0][nt]);
                sacc[1][nt] = MFMA_B16(qf[1][kf2], kfr, sacc[1][nt]);
            }
        }
#pragma unroll
        for (int mt = 0; mt < 2; mt++) {
#pragma unroll
            for (int i = 0; i < 4; i++) {
                float mx = sacc[mt][0][i];
#pragma unroll
                for (int nt = 1; nt < 8; nt++) mx = fmaxf(mx, sacc[mt][nt][i]);
#pragma unroll
                for (int off = 1; off < 16; off <<= 1) mx = fmaxf(mx, __shfl_xor(mx, off));
                float mnew = fmaxf(m_run[mt][i], mx);
                float corr = __expf(m_run[mt][i] - mnew);
                m_run[mt][i] = mnew;
                int row = 16 * mt + 4 * g + i;
                int swp = (row & 7) << 4;
                float rs = 0.f;
#pragma unroll
                for (int nt = 0; nt < 8; nt++) {
                    float p = __expf(sacc[mt][nt][i] - mnew);
                    rs += p;
                    int key = lr + 16 * nt;
                    *(ushort*)(smem + row * 256 + ((2 * key) ^ swp)) = f2bf(p);
                }
#pragma unroll
                for (int off = 1; off < 16; off <<= 1) rs += __shfl_xor(rs, off);
                l_run[mt][i] = l_run[mt][i] * corr + rs;
#pragma unroll
                for (int nt = 0; nt < 4; nt++) oacc[mt][nt][i] *= corr;
            }
        }
        LGKM0();
#pragma unroll
        for (int kc = 0; kc < 4; kc++) {
            bf16x8 pfr[2];
#pragma unroll
            for (int mt = 0; mt < 2; mt++) {
                int prow = 16 * mt + lr;
                pfr[mt] = *(const bf16x8*)(smem + prow * 256 + ((64 * kc + 16 * g) ^ ((prow & 7) << 4)));
            }
#pragma unroll
            for (int nt4 = 0; nt4 < 4; nt4++) {
                bf16x8 vfr = *(const bf16x8*)(vB + ((size_t)((s * 4 + nt4) * 8 + 4 * t + kc) << 9) + (l << 3));
                oacc[0][nt4] = MFMA_B16(pfr[0], vfr, oacc[0][nt4]);
                oacc[1][nt4] = MFMA_B16(pfr[1], vfr, oacc[1][nt4]);
            }
        }
        LGKM0();
    }

#pragma unroll
    for (int mt = 0; mt < 2; mt++)
#pragma unroll
        for (int i = 0; i < 4; i++) {
            float rl = 1.0f / l_run[mt][i];
            int row = 4 * g + i + 16 * mt;
            int swo = (row & 7) << 4;
#pragma unroll
            for (int nt = 0; nt < 4; nt++) {
                int col = lr + 16 * nt;
                *(ushort*)(smem + row * 128 + ((2 * col) ^ swo)) = f2bf(oacc[mt][nt][i] * rl);
            }
        }
    LGKM0();
    bf16x8 ofr[2][2];
#pragma unroll
    for (int mt = 0; mt < 2; mt++)
#pragma unroll
        for (int kf2 = 0; kf2 < 2; kf2++) {
            int row = 16 * mt + lr;
            int rd = row * 128 + ((64 * kf2 + 16 * g) ^ ((row & 7) << 4));
            ofr[mt][kf2] = *(const bf16x8*)(smem + rd);
        }
#pragma unroll
    for (int nt = 0; nt < 8; nt++) {
        f32x4 acc2[2];
        acc2[0] = (f32x4){0.f, 0.f, 0.f, 0.f};
        acc2[1] = (f32x4){0.f, 0.f, 0.f, 0.f};
#pragma unroll
        for (int kf2 = 0; kf2 < 2; kf2++) {
            bf16x8 wfr = *(const bf16x8*)(wroF + (((nt << 1) | kf2) << 9) + (l << 3));
            acc2[0] = MFMA_B16(ofr[0][kf2], wfr, acc2[0]);
            acc2[1] = MFMA_B16(ofr[1][kf2], wfr, acc2[1]);
        }
        int col = lr + 16 * nt;
        float brod = bro[col];
#pragma unroll
        for (int mt = 0; mt < 2; mt++)
#pragma unroll
            for (int i = 0; i < 4; i++) {
                int row = 32 * qc + 16 * mt + 4 * g + i;
                size_t off = (size_t)s * 32768 + (size_t)row * 128 + col;
                x[off] = x[off] + acc2[mt][i] + brod;
            }
    }
}

// ---------------------------------------------------------------------------
// E (fused MFMA attention) — FALLBACK when ws is too small for the split path.
// ---------------------------------------------------------------------------
__global__ __launch_bounds__(512, 2) void k_attn_mfma(
    float* __restrict__ x,
    const float* __restrict__ rn_g, const float* __restrict__ rn_b,
    const ushort* __restrict__ wqF, const ushort* __restrict__ wkF,
    const ushort* __restrict__ wvF, const float* __restrict__ brv,
    const float* __restrict__ Wro, const float* __restrict__ bro)
{
    __shared__ __align__(16) unsigned char smem[131072];

    int tid = threadIdx.x;
    int w  = tid >> 6;
    int l  = tid & 63;
    int g  = l >> 4;
    int lr = l & 15;
    size_t base = (size_t)blockIdx.x * 32768;

    float gl0 = rn_g[l], gl1 = rn_g[l + 64];
    float el0 = rn_b[l], el1 = rn_b[l + 64];

    for (int h = 0; h < 2; h++) {
        for (int rr = 0; rr < 16; rr++) {
            int rloc = 16 * w + rr;
            size_t ro = base + (size_t)(128 * h + rloc) * 128;
            float x0 = x[ro + l], x1 = x[ro + l + 64];
            float s = x0 + x1, q = x0 * x0 + x1 * x1;
#pragma unroll
            for (int off = 32; off; off >>= 1) { s += __shfl_xor(s, off); q += __shfl_xor(q, off); }
            float mu = s * (1.0f / 128.0f);
            float var = q * (1.0f / 128.0f) - mu * mu;
            float rs = rsqrtf(var + 1e-5f);
            int sw = (rloc & 7) << 4;
            *(ushort*)(smem + 65536 + rloc * 256 + ((2 * l) ^ sw))        = f2bf((x0 - mu) * rs * gl0 + el0);
            *(ushort*)(smem + 65536 + rloc * 256 + ((2 * (l + 64)) ^ sw)) = f2bf((x1 - mu) * rs * gl1 + el1);
        }
        LGKM0();

        bf16x8 afr[4];
        int arow = 16 * w + lr;
#pragma unroll
        for (int kf = 0; kf < 4; kf++) {
            int ab = 65536 + arow * 256 + ((16 * g + 64 * kf) ^ ((arow & 7) << 4));
            afr[kf] = *(const bf16x8*)(smem + ab);
        }
#pragma unroll
        for (int m = 0; m < 3; m++) {
            const ushort* wT = (m == 0) ? wqF : (m == 1) ? wkF : wvF;
            f32x4 acc[4];
#pragma unroll
            for (int nt = 0; nt < 4; nt++) acc[nt] = (f32x4){0.f, 0.f, 0.f, 0.f};
#pragma unroll
            for (int kf = 0; kf < 4; kf++) {
#pragma unroll
                for (int nt = 0; nt < 4; nt++) {
                    bf16x8 bfr = *(const bf16x8*)(wT + (((nt << 2) | kf) << 9) + (l << 3));
                    acc[nt] = MFMA_B16(afr[kf], bfr, acc[nt]);
                }
            }
#pragma unroll
            for (int nt = 0; nt < 4; nt++) {
                int col = lr + 16 * nt;
                float bv = (m == 2) ? brv[col] : 0.f;
#pragma unroll
                for (int i = 0; i < 4; i++) {
                    int qrow = 128 * h + 16 * w + 4 * g + i;
                    float v = acc[nt][i];
                    if (m == 0) {
                        int ad = 98304 + qrow * 128 + ((2 * col) ^ ((qrow & 7) << 4));
                        *(ushort*)(smem + ad) = f2bf(v * 0.125f);
                    } else if (m == 1) {
                        int ad = qrow * 128 + ((2 * col) ^ ((qrow & 7) << 4));
                        *(ushort*)(smem + ad) = f2bf(v);
                    } else {
                        int ad = 32768 + col * 512 + ((2 * qrow) ^ ((col & 7) << 4));
                        *(ushort*)(smem + ad) = f2bf(v + bv);
                    }
                }
            }
        }
    }
    __syncthreads();

    bf16x8 qf[2][2];
#pragma unroll
    for (int mt = 0; mt < 2; mt++)
#pragma unroll
        for (int kf = 0; kf < 2; kf++) {
            int qrow = 32 * w + 16 * mt + lr;
            int ab = 98304 + qrow * 128 + ((16 * g + 64 * kf) ^ ((qrow & 7) << 4));
            qf[mt][kf] = *(const bf16x8*)(smem + ab);
        }
    __syncthreads();

    float m_run[2][4], l_run[2][4];
    f32x4 oacc[2][4];
#pragma unroll
    for (int mt = 0; mt < 2; mt++)
#pragma unroll
        for (int i = 0; i < 4; i++) { m_run[mt][i] = -INFINITY; l_run[mt][i] = 0.f; }
#pragma unroll
    for (int mt = 0; mt < 2; mt++)
#pragma unroll
        for (int nt = 0; nt < 4; nt++) oacc[mt][nt] = (f32x4){0.f, 0.f, 0.f, 0.f};

    for (int t = 0; t < 2; t++) {
        f32x4 sacc[2][8];
#pragma unroll
        for (int mt = 0; mt < 2; mt++)
#pragma unroll
            for (int nt = 0; nt < 8; nt++) sacc[mt][nt] = (f32x4){0.f, 0.f, 0.f, 0.f};
#pragma unroll
        for (int nt = 0; nt < 8; nt++) {
#pragma unroll
            for (int kf = 0; kf < 2; kf++) {
                int key = 128 * t + 16 * nt + lr;
                int ab = key * 128 + ((16 * g + 64 * kf) ^ ((key & 7) << 4));
                bf16x8 bfr = *(const bf16x8*)(smem + ab);
#pragma unroll
                for (int mt = 0; mt < 2; mt++)
                    sacc[mt][nt] = MFMA_B16(qf[mt][kf], bfr, sacc[mt][nt]);
            }
        }
#pragma unroll
        for (int mt = 0; mt < 2; mt++) {
#pragma unroll
            for (int i = 0; i < 4; i++) {
                float mx = sacc[mt][0][i];
#pragma unroll
                for (int nt = 1; nt < 8; nt++) mx = fmaxf(mx, sacc[mt][nt][i]);
#pragma unroll
                for (int off = 1; off < 16; off <<= 1) mx = fmaxf(mx, __shfl_xor(mx, off));
                float mnew = fmaxf(m_run[mt][i], mx);
                float corr = __expf(m_run[mt][i] - mnew);
                m_run[mt][i] = mnew;
                int qrow = 32 * w + 16 * mt + 4 * g + i;
                int swq = (qrow & 7) << 4;
                float rs = 0.f;
#pragma unroll
                for (int nt = 0; nt < 8; nt++) {
                    float p = __expf(sacc[mt][nt][i] - mnew);
                    rs += p;
                    int col = lr + 16 * nt;
                    *(ushort*)(smem + 65536 + qrow * 256 + ((2 * col) ^ swq)) = f2bf(p);
                }
#pragma unroll
                for (int off = 1; off < 16; off <<= 1) rs += __shfl_xor(rs, off);
                l_run[mt][i] = l_run[mt][i] * corr + rs;
#pragma unroll
                for (int nt = 0; nt < 4; nt++) oacc[mt][nt][i] *= corr;
            }
        }
        LGKM0();

#pragma unroll
        for (int kf = 0; kf < 4; kf++) {
            bf16x8 pfr[2];
#pragma unroll
            for (int mt = 0; mt < 2; mt++) {
                int qrow = 32 * w + 16 * mt + lr;
                int ab = 65536 + qrow * 256 + ((16 * g + 64 * kf) ^ ((qrow & 7) << 4));
                pfr[mt] = *(const bf16x8*)(smem + ab);
            }
#pragma unroll
            for (int nt = 0; nt < 4; nt++) {
                int d = lr + 16 * nt;
                int bb = 32768 + d * 512 + ((16 * g + 64 * kf + 256 * t) ^ ((d & 7) << 4));
                bf16x8 bfr = *(const bf16x8*)(smem + bb);
#pragma unroll
                for (int mt = 0; mt < 2; mt++)
                    oacc[mt][nt] = MFMA_B16(pfr[mt], bfr, oacc[mt][nt]);
            }
        }
    }
    __syncthreads();

#pragma unroll
    for (int mt = 0; mt < 2; mt++)
#pragma unroll
        for (int i = 0; i < 4; i++) {
            float rl = 1.0f / l_run[mt][i];
            int qrow = 32 * w + 16 * mt + 4 * g + i;
            int swq = (qrow & 7) << 4;
#pragma unroll
            for (int nt = 0; nt < 4; nt++) {
                int col = lr + 16 * nt;
                *(ushort*)(smem + 65536 + qrow * 128 + ((2 * col) ^ swq)) = f2bf(oacc[mt][nt][i] * rl);
            }
        }
    for (int e = tid; e < 8192; e += 512) {
        int k = e >> 7, c = e & 127;
        int ad = c * 128 + ((2 * k) ^ ((c & 7) << 4));
        *(ushort*)(smem + ad) = f2bf(Wro[e]);
    }
    __syncthreads();

#pragma unroll
    for (int mt = 0; mt < 2; mt++) {
        bf16x8 ofr[2];
#pragma unroll
        for (int kf = 0; kf < 2; kf++) {
            int orow = 32 * w + 16 * mt + lr;
            int ab = 65536 + orow * 128 + ((16 * g + 64 * kf) ^ ((orow & 7) << 4));
            ofr[kf] = *(const bf16x8*)(smem + ab);
        }
#pragma unroll
        for (int nt = 0; nt < 8; nt++) {
            f32x4 acc = (f32x4){0.f, 0.f, 0.f, 0.f};
#pragma unroll
            for (int kf = 0; kf < 2; kf++) {
                int c = lr + 16 * nt;
                int bb = c * 128 + ((16 * g + 64 * kf) ^ ((c & 7) << 4));
                bf16x8 bfr = *(const bf16x8*)(smem + bb);
                acc = MFMA_B16(ofr[kf], bfr, acc);
            }
            int col = lr + 16 * nt;
            float brod = bro[col];
#pragma unroll
            for (int i = 0; i < 4; i++) {
                int qrow = 32 * w + 16 * mt + 4 * g + i;
                size_t off = base + (size_t)qrow * 128 + col;
                x[off] = x[off] + acc[i] + brod;
            }
        }
    }
}

// ---------------------------------------------------------------------------
// F (MFMA MLP v6, barrier-free; proven at (64,4)).
// ---------------------------------------------------------------------------
__global__ __launch_bounds__(64, 4) void k_mlp_mfma(
    float* __restrict__ x,
    const float* __restrict__ mn_g, const float* __restrict__ mn_b,
    const ushort* __restrict__ w1F, const ushort* __restrict__ w2F,
    const float* __restrict__ b1, const float* __restrict__ b2)
{
    __shared__ __align__(16) unsigned char smem[5120];
    int l = threadIdx.x;
    int g = l >> 4, lr = l & 15;
    size_t rbase = (size_t)blockIdx.x * 16;

    {
        float gl0 = mn_g[l], gl1 = mn_g[l + 64];
        float el0 = mn_b[l], el1 = mn_b[l + 64];
#pragma unroll
        for (int bb = 0; bb < 4; bb++) {
            float a0[4], a1[4];
#pragma unroll
            for (int rr = 0; rr < 4; rr++) {
                size_t ro = (rbase + 4 * bb + rr) * 128;
                a0[rr] = x[ro + l];
                a1[rr] = x[ro + l + 64];
            }
#pragma unroll
            for (int rr = 0; rr < 4; rr++) {
                int rloc = 4 * bb + rr;
                float x0 = a0[rr], x1 = a1[rr];
                float s = x0 + x1, q = x0 * x0 + x1 * x1;
#pragma unroll
                for (int off = 32; off; off >>= 1) { s += __shfl_xor(s, off); q += __shfl_xor(q, off); }
                float mu = s * (1.0f / 128.0f);
                float var = q * (1.0f / 128.0f) - mu * mu;
                float rs = rsqrtf(var + 1e-5f);
                int sw = (rloc & 7) << 4;
                *(ushort*)(smem + rloc * 256 + ((2 * l) ^ sw))        = f2bf((x0 - mu) * rs * gl0 + el0);
                *(ushort*)(smem + rloc * 256 + ((2 * (l + 64)) ^ sw)) = f2bf((x1 - mu) * rs * gl1 + el1);
            }
        }
    }
    LGKM0();

    bf16x8 afr[4];
#pragma unroll
    for (int kf = 0; kf < 4; kf++) {
        afr[kf] = *(const bf16x8*)(smem + lr * 256 + ((16 * g + 64 * kf) ^ ((lr & 7) << 4)));
    }

    f32x4 oacc[8];
#pragma unroll
    for (int nt = 0; nt < 8; nt++) oacc[nt] = (f32x4){0.f, 0.f, 0.f, 0.f};

#pragma unroll
    for (int kb = 0; kb < 2; kb++) {
#pragma unroll
        for (int cc = 0; cc < 4; cc++) {
#pragma unroll
            for (int nt2 = 0; nt2 < 2; nt2++) {
                int nt = 2 * cc + nt2;
                f32x4 acc = (f32x4){0.f, 0.f, 0.f, 0.f};
#pragma unroll
                for (int kf = 0; kf < 4; kf++) {
                    bf16x8 bfr = *(const bf16x8*)(w1F + (((((kb << 3) | nt) << 2) | kf) << 9) + (l << 3));
                    acc = MFMA_B16(afr[kf], bfr, acc);
                }
                float bb1 = b1[128 * kb + 16 * nt + lr];
                int colc = lr + 16 * nt2;
#pragma unroll
                for (int i = 0; i < 4; i++) {
                    int row = 4 * g + i;
                    int ad = 4096 + row * 64 + ((2 * colc) ^ ((row & 3) << 4));
                    *(ushort*)(smem + ad) = f2bf(fmaxf(acc[i] + bb1, 0.f));
                }
            }
            LGKM0();

            bf16x8 hfr = *(const bf16x8*)(smem + 4096 + lr * 64 + ((16 * g) ^ ((lr & 3) << 4)));
#pragma unroll
            for (int nt = 0; nt < 8; nt++) {
                bf16x8 bfr = *(const bf16x8*)(w2F + (((((kb << 3) | nt) << 2) | cc) << 9) + (l << 3));
                oacc[nt] = MFMA_B16(hfr, bfr, oacc[nt]);
            }
            LGKM0();
        }
    }

#pragma unroll
    for (int nt = 0; nt < 8; nt++) {
        int col = 16 * nt + lr;
#pragma unroll
        for (int i = 0; i < 4; i++) {
            int row = 4 * g + i;
            int ad = row * 256 + ((2 * col) ^ ((row & 7) << 4));
            *(ushort*)(smem + ad) = f2bf(oacc[nt][i]);
        }
    }
    LGKM0();
    {
        float b20 = b2[l], b21 = b2[l + 64];
#pragma unroll
        for (int rr = 0; rr < 16; rr++) {
            int sw = (rr & 7) << 4;
            float d0 = lbf(*(const ushort*)(smem + rr * 256 + ((2 * l) ^ sw)));
            float d1 = lbf(*(const ushort*)(smem + rr * 256 + ((2 * (l + 64)) ^ sw)));
            size_t ro = (rbase + rr) * 128;
            x[ro + l]      = x[ro + l]      + d0 + b20;
            x[ro + l + 64] = x[ro + l + 64] + d1 + b21;
        }
    }
}

// ---------------------------------------------------------------------------
extern "C" void kernel_launch(void* const* d_in, const int* in_sizes, int n_in,
                              void* d_out, int out_size, void* d_ws, size_t ws_size,
                              hipStream_t stream)
{
    const float* seq   = (const float*)d_in[0];
    const float* pair  = (const float*)d_in[1];
    const float* sn_g  = (const float*)d_in[2];
    const float* sn_b  = (const float*)d_in[3];
    const float* Wq    = (const float*)d_in[4];
    const float* Wk    = (const float*)d_in[5];
    const float* Wyq   = (const float*)d_in[6];
    const float* Wyk   = (const float*)d_in[7];
    const float* Wdist = (const float*)d_in[8];
    const float* Wout  = (const float*)d_in[9];
    const float* bout  = (const float*)d_in[10];
    const float* rn_g  = (const float*)d_in[11];
    const float* rn_b  = (const float*)d_in[12];
    const float* Wrq   = (const float*)d_in[13];
    const float* Wrk   = (const float*)d_in[14];
    const float* Wrv   = (const float*)d_in[15];
    const float* brv   = (const float*)d_in[16];
    const float* Wro   = (const float*)d_in[17];
    const float* bro   = (const float*)d_in[18];
    const float* mn_g  = (const float*)d_in[19];
    const float* mn_b  = (const float*)d_in[20];
    const float* W1    = (const float*)d_in[21];
    const float* b1    = (const float*)d_in[22];
    const float* W2    = (const float*)d_in[23];
    const float* b2    = (const float*)d_in[24];
    (void)in_sizes; (void)n_in; (void)out_size;

    float*  x2   = (float*)d_ws;           // 262144 f32
    float*  a2   = x2 + 262144;            // 65536
    float*  c2   = a2 + 65536;             // 65536
    float*  wd2  = c2 + 65536;             // 512
    ushort* wqF  = (ushort*)(wd2 + 512);   // 8192 each
    ushort* wkF  = wqF + 8192;
    ushort* wvF  = wkF + 8192;
    ushort* wroF = wvF + 8192;             // 8192
    ushort* w1F  = wroF + 8192;            // 32768
    ushort* w2F  = w1F + 32768;            // 32768
    ushort* qA   = w2F + 32768;            // 8388608 each (split path only)
    ushort* kBp  = qA + 8388608;
    ushort* vBp  = kBp + 8388608;
    float*  xres = (float*)d_out;

    const size_t WS_NEED_SPLIT = 52103168ull;   // bytes incl. qA/kB/vB
    bool use_split = (ws_size >= WS_NEED_SPLIT);

    k_ln_pool  <<<512,   256, 0, stream>>>(seq, sn_g, sn_b, x2);
    k_proj     <<<512,   128, 0, stream>>>(x2, Wq, Wk, Wyq, Wyk, Wout, bout, a2, c2);
    k_wd2      <<<1,     128, 0, stream>>>(Wdist, Wout, wd2);
    k_wt       <<<64,    512, 0, stream>>>(Wrq, Wrk, Wrv, Wro, wqF, wkF, wvF, wroF);
    k_wt12     <<<128,   512, 0, stream>>>(W1, W2, w1F, w2F);
    if (use_split) {
        k_qkv_asm<<<4096, 64,  0, stream>>>(xres, pair, a2, c2, wd2,
                                            rn_g, rn_b, wqF, wkF, wvF, brv,
                                            qA, kBp, vBp);
        k_attn2  <<<2048, 128, 0, stream>>>(xres, qA, kBp, vBp, wroF, bro);
    } else {
        k_assemble <<<65536, 256, 0, stream>>>(pair, a2, c2, wd2, xres);
        k_attn_mfma<<<512,   512, 0, stream>>>(xres, rn_g, rn_b, wqF, wkF, wvF, brv, Wro, bro);
    }
    k_mlp_mfma <<<8192,  64,  0, stream>>>(xres, mn_g, mn_b, w1F, w2F, b1, b2);
}

// Round 24
// 208.876 us; speedup vs baseline: 1.3611x; 1.0085x over previous
//
#include <hip/hip_runtime.h>
#include <hip/hip_bf16.h>

using bf16 = __hip_bfloat16;
typedef unsigned int uint;
typedef unsigned short ushort;
typedef __attribute__((ext_vector_type(8))) short bf16x8;
typedef __attribute__((ext_vector_type(4))) float f32x4;

// Shapes: B=2, S=512, SD=512, P=256, PD=128, AD=64, H=256
// All global tensors are f32.
// FINAL configuration (rounds 21/23: 209.4/210.7 us; baseline 1074.7 us).

__device__ __forceinline__ float bfraw(uint u) { return __uint_as_float(u << 16); }
__device__ __forceinline__ ushort f2bf(float f) {
    bf16 h = __float2bfloat16(f);
    return *reinterpret_cast<ushort*>(&h);
}
__device__ __forceinline__ float lbf(ushort u) { return __uint_as_float(((uint)u) << 16); }

#define MFMA_B16(a, b, c) __builtin_amdgcn_mfma_f32_16x16x32_bf16((a), (b), (c), 0, 0, 0)
#define LGKM0() asm volatile("s_waitcnt lgkmcnt(0)" ::: "memory")

// ---------------------------------------------------------------------------
// A: LayerNorm(seq) over SD=512 + avg-pool row pairs -> x2 f32. 512 blocks.
// ---------------------------------------------------------------------------
__global__ __launch_bounds__(256) void k_ln_pool(
    const float* __restrict__ seq, const float* __restrict__ g,
    const float* __restrict__ be, float* __restrict__ x2)
{
    __shared__ float red[4][4];
    int bp = blockIdx.x;
    int t  = threadIdx.x;
    const float* r0 = seq + (size_t)(bp * 2) * 512;
    const float* r1 = r0 + 512;

    float a0 = r0[t], a1 = r0[t + 256];
    float c0 = r1[t], c1 = r1[t + 256];

    float s0 = a0 + a1, q0 = a0 * a0 + a1 * a1;
    float s1 = c0 + c1, q1 = c0 * c0 + c1 * c1;
#pragma unroll
    for (int off = 32; off; off >>= 1) {
        s0 += __shfl_xor(s0, off); q0 += __shfl_xor(q0, off);
        s1 += __shfl_xor(s1, off); q1 += __shfl_xor(q1, off);
    }
    int w = t >> 6, l = t & 63;
    if (l == 0) { red[0][w] = s0; red[1][w] = q0; red[2][w] = s1; red[3][w] = q1; }
    __syncthreads();
    s0 = red[0][0] + red[0][1] + red[0][2] + red[0][3];
    q0 = red[1][0] + red[1][1] + red[1][2] + red[1][3];
    s1 = red[2][0] + red[2][1] + red[2][2] + red[2][3];
    q1 = red[3][0] + red[3][1] + red[3][2] + red[3][3];

    const float inv = 1.0f / 512.0f;
    float mu0 = s0 * inv, var0 = q0 * inv - mu0 * mu0, rs0 = rsqrtf(var0 + 1e-5f);
    float mu1 = s1 * inv, var1 = q1 * inv - mu1 * mu1, rs1 = rsqrtf(var1 + 1e-5f);

    float g0 = g[t], g1 = g[t + 256];
    float e0 = be[t], e1 = be[t + 256];

    float o0 = 0.5f * ((a0 - mu0) * rs0 * g0 + e0 + (c0 - mu1) * rs1 * g0 + e0);
    float o1 = 0.5f * ((a1 - mu0) * rs0 * g1 + e1 + (c1 - mu1) * rs1 * g1 + e1);

    float* xo = x2 + (size_t)bp * 512;
    xo[t] = o0; xo[t + 256] = o1;
}

// ---------------------------------------------------------------------------
// B: A2 = (x@Wq + gelu(x)@Wyq)@Wout + bout ; C2 = (x@Wk + gelu(x)@Wyk)@Wout
// ---------------------------------------------------------------------------
__global__ __launch_bounds__(128) void k_proj(
    const float* __restrict__ x2,
    const float* __restrict__ Wq, const float* __restrict__ Wk,
    const float* __restrict__ Wyq, const float* __restrict__ Wyk,
    const float* __restrict__ Wout, const float* __restrict__ bout,
    float* __restrict__ a2, float* __restrict__ c2)
{
    __shared__ float xr[512], gxr[512], ar[128], cr[128];
    int row = blockIdx.x;
    int t   = threadIdx.x;

    for (int u = t; u < 512; u += 128) {
        float v = x2[(size_t)row * 512 + u];
        xr[u]  = v;
        gxr[u] = 0.5f * v * (1.0f + erff(v * 0.70710678118654752f));
    }
    __syncthreads();

    float a = 0.f, c = 0.f;
    for (int s = 0; s < 512; s++) {
        float xs = xr[s], gs = gxr[s];
        a += xs * Wq[s * 128 + t] + gs * Wyq[s * 128 + t];
        c += xs * Wk[s * 128 + t] + gs * Wyk[s * 128 + t];
    }
    ar[t] = a; cr[t] = c;
    __syncthreads();

    float A = bout[t], C = 0.f;
    for (int u = 0; u < 128; u++) {
        float wv = Wout[u * 128 + t];
        A += ar[u] * wv;
        C += cr[u] * wv;
    }
    a2[(size_t)row * 128 + t] = A;
    c2[(size_t)row * 128 + t] = C;
}

// ---------------------------------------------------------------------------
// W: Wd2 = Wdist(3x128) @ Wout(128x128)
// ---------------------------------------------------------------------------
__global__ __launch_bounds__(128) void k_wd2(
    const float* __restrict__ Wdist, const float* __restrict__ Wout,
    float* __restrict__ wd2)
{
    int t = threadIdx.x;
#pragma unroll
    for (int f = 0; f < 3; f++) {
        float acc = 0.f;
        for (int u = 0; u < 128; u++)
            acc += Wdist[f * 128 + u] * Wout[u * 128 + t];
        wd2[f * 128 + t] = acc;
    }
}

// ---------------------------------------------------------------------------
// WT prep (FRAGMENT-ORDER). m=0..2: Wrq/Wrk/Wrv; m=3: Wro.
// ---------------------------------------------------------------------------
__global__ __launch_bounds__(512) void k_wt(
    const float* __restrict__ Wrq, const float* __restrict__ Wrk,
    const float* __restrict__ Wrv, const float* __restrict__ Wro,
    ushort* __restrict__ wqF, ushort* __restrict__ wkF,
    ushort* __restrict__ wvF, ushort* __restrict__ wroF)
{
    int idx = blockIdx.x * 512 + threadIdx.x;       // 0 .. 4*8192
    int m = idx >> 13;
    int o = idx & 8191;
    int f = o >> 9;            // 0..15
    int l = (o >> 3) & 63;
    int j = o & 7;
    if (m < 3) {
        int nt = f >> 2, kf = f & 3;
        const float* W = (m == 0) ? Wrq : (m == 1) ? Wrk : Wrv;
        ushort* T = (m == 0) ? wqF : (m == 1) ? wkF : wvF;
        T[o] = f2bf(W[(32 * kf + 8 * (l >> 4) + j) * 64 + 16 * nt + (l & 15)]);
    } else {
        int nt = f >> 1, kf2 = f & 1;
        wroF[o] = f2bf(Wro[(32 * kf2 + 8 * (l >> 4) + j) * 128 + 16 * nt + (l & 15)]);
    }
}

// ---------------------------------------------------------------------------
// WT prep 2 (MLP, FRAGMENT-ORDER)
// ---------------------------------------------------------------------------
__global__ __launch_bounds__(512) void k_wt12(
    const float* __restrict__ W1, const float* __restrict__ W2,
    ushort* __restrict__ w1F, ushort* __restrict__ w2F)
{
    int idx = blockIdx.x * 512 + threadIdx.x;   // 0 .. 65536
    int o = idx & 32767;
    int f = o >> 9;            // 0..63
    int l = (o >> 3) & 63;
    int j = o & 7;
    int kb = f >> 5, nt = (f >> 2) & 7, kf = f & 3;
    if (idx < 32768) {
        int R = 128 * kb + 16 * nt + (l & 15);
        int C = 32 * kf + 8 * (l >> 4) + j;
        w1F[o] = f2bf(W1[C * 256 + R]);
    } else {
        int R2 = 16 * nt + (l & 15);
        int C2 = 128 * kb + 32 * kf + 8 * (l >> 4) + j;
        w2F[o] = f2bf(W2[C2 * 128 + R2]);
    }
}

// ---------------------------------------------------------------------------
// C: assemble (FALLBACK path only)
// ---------------------------------------------------------------------------
__global__ __launch_bounds__(256) void k_assemble(
    const float* __restrict__ pair, const float* __restrict__ a2,
    const float* __restrict__ c2, const float* __restrict__ wd2,
    float* __restrict__ xout)
{
    size_t idx = (size_t)blockIdx.x * 256 + threadIdx.x;
    int d = (int)(idx & 127);
    size_t r = idx >> 7;
    int j = (int)(r & 255); r >>= 8;
    int i = (int)(r & 255);
    int b = (int)(r >> 8);

    float ds = fabsf((float)(i - j)) * (1.0f / 255.0f);
    float sg = (float)((i > j) - (i < j));
    float ex = __expf(-ds);

    float v = pair[idx]
            + a2[(size_t)(b * 256 + i) * 128 + d]
            + c2[(size_t)(b * 256 + j) * 128 + d]
            + ds * wd2[d] + sg * wd2[128 + d] + ex * wd2[256 + d];
    xout[idx] = v;
}

// ---------------------------------------------------------------------------
// QKV + ASSEMBLE (split path, fused; proven round 21).
// ---------------------------------------------------------------------------
__global__ __launch_bounds__(64, 2) void k_qkv_asm(
    float* __restrict__ x, const float* __restrict__ pair,
    const float* __restrict__ a2, const float* __restrict__ c2,
    const float* __restrict__ wd2,
    const float* __restrict__ rn_g, const float* __restrict__ rn_b,
    const ushort* __restrict__ wqF, const ushort* __restrict__ wkF,
    const ushort* __restrict__ wvF, const float* __restrict__ brv,
    ushort* __restrict__ qA, ushort* __restrict__ kB, ushort* __restrict__ vB)
{
    __shared__ __align__(16) unsigned char smem[12288];
    int l = threadIdx.x;
    int g = l >> 4, lr = l & 15;
    int s = blockIdx.x & 511;
    int c = blockIdx.x >> 9;
    size_t xbase = (size_t)s * 32768 + (size_t)(32 * c) * 128;

    {
        float gl0 = rn_g[l], gl1 = rn_g[l + 64];
        float el0 = rn_b[l], el1 = rn_b[l + 64];
        int b  = s >> 8;
        int ii = s & 255;
        float a20 = a2[(size_t)s * 128 + l];
        float a21 = a2[(size_t)s * 128 + l + 64];
        float wdA0 = wd2[l],       wdA1 = wd2[l + 64];
        float wdB0 = wd2[128 + l], wdB1 = wd2[128 + l + 64];
        float wdC0 = wd2[256 + l], wdC1 = wd2[256 + l + 64];
#pragma unroll
        for (int bb = 0; bb < 8; bb++) {
            float p0[4], p1[4], c20[4], c21[4];
#pragma unroll
            for (int rr = 0; rr < 4; rr++) {
                size_t ro = xbase + (size_t)(4 * bb + rr) * 128;
                p0[rr] = pair[ro + l]; p1[rr] = pair[ro + l + 64];
                int j = 32 * c + 4 * bb + rr;
                c20[rr] = c2[(size_t)(b * 256 + j) * 128 + l];
                c21[rr] = c2[(size_t)(b * 256 + j) * 128 + l + 64];
            }
#pragma unroll
            for (int rr = 0; rr < 4; rr++) {
                int rloc = 4 * bb + rr;
                int j = 32 * c + rloc;
                float dsv = fabsf((float)(ii - j)) * (1.0f / 255.0f);
                float sgv = (float)((ii > j) - (ii < j));
                float exv = __expf(-dsv);
                float x0 = p0[rr] + a20 + c20[rr] + dsv * wdA0 + sgv * wdB0 + exv * wdC0;
                float x1 = p1[rr] + a21 + c21[rr] + dsv * wdA1 + sgv * wdB1 + exv * wdC1;
                size_t ro = xbase + (size_t)rloc * 128;
                x[ro + l] = x0; x[ro + l + 64] = x1;
                float sS = x0 + x1, qS = x0 * x0 + x1 * x1;
#pragma unroll
                for (int off = 32; off; off >>= 1) { sS += __shfl_xor(sS, off); qS += __shfl_xor(qS, off); }
                float mu = sS * (1.0f / 128.0f);
                float var = qS * (1.0f / 128.0f) - mu * mu;
                float rs = rsqrtf(var + 1e-5f);
                int sw = (rloc & 7) << 4;
                *(ushort*)(smem + rloc * 256 + ((2 * l) ^ sw))        = f2bf((x0 - mu) * rs * gl0 + el0);
                *(ushort*)(smem + rloc * 256 + ((2 * (l + 64)) ^ sw)) = f2bf((x1 - mu) * rs * gl1 + el1);
            }
        }
    }
    LGKM0();

    bf16x8 afr[2][4];
#pragma unroll
    for (int mt = 0; mt < 2; mt++)
#pragma unroll
        for (int kf = 0; kf < 4; kf++) {
            int row = 16 * mt + lr;
            afr[mt][kf] = *(const bf16x8*)(smem + row * 256 + ((16 * g + 64 * kf) ^ ((row & 7) << 4)));
        }

    unsigned char* dscr = smem + 8192;

#pragma unroll
    for (int mqk = 0; mqk < 2; mqk++) {
        const ushort* wF = mqk ? wkF : wqF;
        ushort* dst = mqk ? kB : qA;
        float scale = mqk ? 1.0f : 0.125f;
#pragma unroll
        for (int mt = 0; mt < 2; mt++) {
#pragma unroll
            for (int nt = 0; nt < 4; nt++) {
                f32x4 acc = (f32x4){0.f, 0.f, 0.f, 0.f};
#pragma unroll
                for (int kf = 0; kf < 4; kf++) {
                    bf16x8 bfr = *(const bf16x8*)(wF + (((nt << 2) | kf) << 9) + (l << 3));
                    acc = MFMA_B16(afr[mt][kf], bfr, acc);
                }
                int col = lr + 16 * nt;
#pragma unroll
                for (int i = 0; i < 4; i++) {
                    int row = 4 * g + i + 16 * mt;
                    int ad = row * 128 + ((2 * col) ^ ((row & 7) << 4));
                    *(ushort*)(dscr + ad) = f2bf(acc[i] * scale);
                }
            }
        }
        LGKM0();
#pragma unroll
        for (int mt = 0; mt < 2; mt++)
#pragma unroll
            for (int kf2 = 0; kf2 < 2; kf2++) {
                int row = 16 * mt + lr;
                int rd = row * 128 + ((64 * kf2 + 16 * g) ^ ((row & 7) << 4));
                bf16x8 v = *(const bf16x8*)(dscr + rd);
                *(bf16x8*)(dst + ((size_t)((s * 16 + 2 * c + mt) * 2 + kf2) << 9) + (l << 3)) = v;
            }
        LGKM0();
    }

#pragma unroll
    for (int mt = 0; mt < 2; mt++) {
#pragma unroll
        for (int nt = 0; nt < 4; nt++) {
            f32x4 acc = (f32x4){0.f, 0.f, 0.f, 0.f};
#pragma unroll
            for (int kf = 0; kf < 4; kf++) {
                bf16x8 bfr = *(const bf16x8*)(wvF + (((nt << 2) | kf) << 9) + (l << 3));
                acc = MFMA_B16(afr[mt][kf], bfr, acc);
            }
            int d = lr + 16 * nt;
            float bv = brv[d];
#pragma unroll
            for (int i = 0; i < 4; i++) {
                int kk = 4 * g + i + 16 * mt;
                int ad = d * 64 + ((2 * kk) ^ ((d & 3) << 4));
                *(ushort*)(dscr + ad) = f2bf(acc[i] + bv);
            }
        }
    }
    LGKM0();
#pragma unroll
    for (int nt2 = 0; nt2 < 4; nt2++) {
        int d = 16 * nt2 + lr;
        int rd = d * 64 + ((16 * g) ^ ((d & 3) << 4));
        bf16x8 vv = *(const bf16x8*)(dscr + rd);
        *(bf16x8*)(vB + ((size_t)((s * 4 + nt2) * 8 + c) << 9) + (l << 3)) = vv;
    }
}

// ---------------------------------------------------------------------------
// Flash + out-proj (split path; proven rounds 18/20/21).
// ---------------------------------------------------------------------------
__global__ __launch_bounds__(128, 2) void k_attn2(
    float* __restrict__ x,
    const ushort* __restrict__ qA, const ushort* __restrict__ kB,
    const ushort* __restrict__ vB, const ushort* __restrict__ wroF,
    const float* __restrict__ bro)
{
    __shared__ __align__(16) unsigned char smem_all[16384];
    int tid = threadIdx.x;
    int w = tid >> 6;
    int l = tid & 63, g = l >> 4, lr = l & 15;
    int s = blockIdx.x & 511;               // slice (XCD-locality)
    int qc = ((blockIdx.x >> 9) << 1) | w;  // q-chunk 0..7
    unsigned char* smem = smem_all + (w << 13);   // private 8KB per wave

    bf16x8 qf[2][2];
#pragma unroll
    for (int mt = 0; mt < 2; mt++)
#pragma unroll
        for (int kf2 = 0; kf2 < 2; kf2++)
            qf[mt][kf2] = *(const bf16x8*)(qA + ((size_t)((s * 16 + 2 * qc + mt) * 2 + kf2) << 9) + (l << 3));

    float m_run[2][4], l_run[2][4];
    f32x4 oacc[2][4];
#pragma unroll
    for (int mt = 0; mt < 2; mt++)
#pragma unroll
        for (int i = 0; i < 4; i++) { m_run[mt][i] = -INFINITY; l_run[mt][i] = 0.f; }
#pragma unroll
    for (int mt = 0; mt < 2; mt++)
#pragma unroll
        for (int nt = 0; nt < 4; nt++) oacc[mt][nt] = (f32x4){0.f, 0.f, 0.f, 0.f};

    for (int t = 0; t < 2; t++) {
        f32x4 sacc[2][8];
#pragma unroll
        for (int mt = 0; mt < 2; mt++)
#pragma unroll
            for (int nt = 0; nt < 8; nt++) sacc[mt][nt] = (f32x4){0.f, 0.f, 0.f, 0.f};
#pragma unroll
        for (int nt = 0; nt < 8; nt++) {
            int kt = 8 * t + nt;
#pragma unroll
            for (int kf2 = 0; kf2 < 2; kf2++) {
                bf16x8 kfr = *(const bf16x8*)(kB + ((size_t)((s * 16 + kt) * 2 + kf2) << 9) + (l << 3));
                sacc[0][nt] = MFMA_B16(qf[0][kf2], kfr, sacc[0][nt]);
                sacc[1][nt] = MFMA_B16(qf[1][kf2], kfr, sacc[1][nt]);
            }
        }
#pragma unroll
        for (int mt = 0; mt < 2; mt++) {
#pragma unroll
            for (int i = 0; i < 4; i++) {
                float mx = sacc[mt][0][i];
#pragma unroll
                for (int nt = 1; nt < 8; nt++) mx = fmaxf(mx, sacc[mt][nt][i]);
#pragma unroll
                for (int off = 1; off < 16; off <<= 1) mx = fmaxf(mx, __shfl_xor(mx, off));
                float mnew = fmaxf(m_run[mt][i], mx);
                float corr = __expf(m_run[mt][i] - mnew);
                m_run[mt][i] = mnew;
                int row = 16 * mt + 4 * g + i;
                int swp = (row & 7) << 4;
                float rs = 0.f;
#pragma unroll
                for (int nt = 0; nt < 8; nt++) {
                    float p = __expf(sacc[mt][nt][i] - mnew);
                    rs += p;
                    int key = lr + 16 * nt;
                    *(ushort*)(smem + row * 256 + ((2 * key) ^ swp)) = f2bf(p);
                }
#pragma unroll
                for (int off = 1; off < 16; off <<= 1) rs += __shfl_xor(rs, off);
                l_run[mt][i] = l_run[mt][i] * corr + rs;
#pragma unroll
                for (int nt = 0; nt < 4; nt++) oacc[mt][nt][i] *= corr;
            }
        }
        LGKM0();
#pragma unroll
        for (int kc = 0; kc < 4; kc++) {
            bf16x8 pfr[2];
#pragma unroll
            for (int mt = 0; mt < 2; mt++) {
                int prow = 16 * mt + lr;
                pfr[mt] = *(const bf16x8*)(smem + prow * 256 + ((64 * kc + 16 * g) ^ ((prow & 7) << 4)));
            }
#pragma unroll
            for (int nt4 = 0; nt4 < 4; nt4++) {
                bf16x8 vfr = *(const bf16x8*)(vB + ((size_t)((s * 4 + nt4) * 8 + 4 * t + kc) << 9) + (l << 3));
                oacc[0][nt4] = MFMA_B16(pfr[0], vfr, oacc[0][nt4]);
                oacc[1][nt4] = MFMA_B16(pfr[1], vfr, oacc[1][nt4]);
            }
        }
        LGKM0();
    }

#pragma unroll
    for (int mt = 0; mt < 2; mt++)
#pragma unroll
        for (int i = 0; i < 4; i++) {
            float rl = 1.0f / l_run[mt][i];
            int row = 4 * g + i + 16 * mt;
            int swo = (row & 7) << 4;
#pragma unroll
            for (int nt = 0; nt < 4; nt++) {
                int col = lr + 16 * nt;
                *(ushort*)(smem + row * 128 + ((2 * col) ^ swo)) = f2bf(oacc[mt][nt][i] * rl);
            }
        }
    LGKM0();
    bf16x8 ofr[2][2];
#pragma unroll
    for (int mt = 0; mt < 2; mt++)
#pragma unroll
        for (int kf2 = 0; kf2 < 2; kf2++) {
            int row = 16 * mt + lr;
            int rd = row * 128 + ((64 * kf2 + 16 * g) ^ ((row & 7) << 4));
            ofr[mt][kf2] = *(const bf16x8*)(smem + rd);
        }
#pragma unroll
    for (int nt = 0; nt < 8; nt++) {
        f32x4 acc2[2];
        acc2[0] = (f32x4){0.f, 0.f, 0.f, 0.f};
        acc2[1] = (f32x4){0.f, 0.f, 0.f, 0.f};
#pragma unroll
        for (int kf2 = 0; kf2 < 2; kf2++) {
            bf16x8 wfr = *(const bf16x8*)(wroF + (((nt << 1) | kf2) << 9) + (l << 3));
            acc2[0] = MFMA_B16(ofr[0][kf2], wfr, acc2[0]);
            acc2[1] = MFMA_B16(ofr[1][kf2], wfr, acc2[1]);
        }
        int col = lr + 16 * nt;
        float brod = bro[col];
#pragma unroll
        for (int mt = 0; mt < 2; mt++)
#pragma unroll
            for (int i = 0; i < 4; i++) {
                int row = 32 * qc + 16 * mt + 4 * g + i;
                size_t off = (size_t)s * 32768 + (size_t)row * 128 + col;
                x[off] = x[off] + acc2[mt][i] + brod;
            }
    }
}

// ---------------------------------------------------------------------------
// E (fused MFMA attention) — FALLBACK when ws is too small for the split path.
// ---------------------------------------------------------------------------
__global__ __launch_bounds__(512, 2) void k_attn_mfma(
    float* __restrict__ x,
    const float* __restrict__ rn_g, const float* __restrict__ rn_b,
    const ushort* __restrict__ wqF, const ushort* __restrict__ wkF,
    const ushort* __restrict__ wvF, const float* __restrict__ brv,
    const float* __restrict__ Wro, const float* __restrict__ bro)
{
    __shared__ __align__(16) unsigned char smem[131072];

    int tid = threadIdx.x;
    int w  = tid >> 6;
    int l  = tid & 63;
    int g  = l >> 4;
    int lr = l & 15;
    size_t base = (size_t)blockIdx.x * 32768;

    float gl0 = rn_g[l], gl1 = rn_g[l + 64];
    float el0 = rn_b[l], el1 = rn_b[l + 64];

    for (int h = 0; h < 2; h++) {
        for (int rr = 0; rr < 16; rr++) {
            int rloc = 16 * w + rr;
            size_t ro = base + (size_t)(128 * h + rloc) * 128;
            float x0 = x[ro + l], x1 = x[ro + l + 64];
            float s = x0 + x1, q = x0 * x0 + x1 * x1;
#pragma unroll
            for (int off = 32; off; off >>= 1) { s += __shfl_xor(s, off); q += __shfl_xor(q, off); }
            float mu = s * (1.0f / 128.0f);
            float var = q * (1.0f / 128.0f) - mu * mu;
            float rs = rsqrtf(var + 1e-5f);
            int sw = (rloc & 7) << 4;
            *(ushort*)(smem + 65536 + rloc * 256 + ((2 * l) ^ sw))        = f2bf((x0 - mu) * rs * gl0 + el0);
            *(ushort*)(smem + 65536 + rloc * 256 + ((2 * (l + 64)) ^ sw)) = f2bf((x1 - mu) * rs * gl1 + el1);
        }
        LGKM0();

        bf16x8 afr[4];
        int arow = 16 * w + lr;
#pragma unroll
        for (int kf = 0; kf < 4; kf++) {
            int ab = 65536 + arow * 256 + ((16 * g + 64 * kf) ^ ((arow & 7) << 4));
            afr[kf] = *(const bf16x8*)(smem + ab);
        }
#pragma unroll
        for (int m = 0; m < 3; m++) {
            const ushort* wT = (m == 0) ? wqF : (m == 1) ? wkF : wvF;
            f32x4 acc[4];
#pragma unroll
            for (int nt = 0; nt < 4; nt++) acc[nt] = (f32x4){0.f, 0.f, 0.f, 0.f};
#pragma unroll
            for (int kf = 0; kf < 4; kf++) {
#pragma unroll
                for (int nt = 0; nt < 4; nt++) {
                    bf16x8 bfr = *(const bf16x8*)(wT + (((nt << 2) | kf) << 9) + (l << 3));
                    acc[nt] = MFMA_B16(afr[kf], bfr, acc[nt]);
                }
            }
#pragma unroll
            for (int nt = 0; nt < 4; nt++) {
                int col = lr + 16 * nt;
                float bv = (m == 2) ? brv[col] : 0.f;
#pragma unroll
                for (int i = 0; i < 4; i++) {
                    int qrow = 128 * h + 16 * w + 4 * g + i;
                    float v = acc[nt][i];
                    if (m == 0) {
                        int ad = 98304 + qrow * 128 + ((2 * col) ^ ((qrow & 7) << 4));
                        *(ushort*)(smem + ad) = f2bf(v * 0.125f);
                    } else if (m == 1) {
                        int ad = qrow * 128 + ((2 * col) ^ ((qrow & 7) << 4));
                        *(ushort*)(smem + ad) = f2bf(v);
                    } else {
                        int ad = 32768 + col * 512 + ((2 * qrow) ^ ((col & 7) << 4));
                        *(ushort*)(smem + ad) = f2bf(v + bv);
                    }
                }
            }
        }
    }
    __syncthreads();

    bf16x8 qf[2][2];
#pragma unroll
    for (int mt = 0; mt < 2; mt++)
#pragma unroll
        for (int kf = 0; kf < 2; kf++) {
            int qrow = 32 * w + 16 * mt + lr;
            int ab = 98304 + qrow * 128 + ((16 * g + 64 * kf) ^ ((qrow & 7) << 4));
            qf[mt][kf] = *(const bf16x8*)(smem + ab);
        }
    __syncthreads();

    float m_run[2][4], l_run[2][4];
    f32x4 oacc[2][4];
#pragma unroll
    for (int mt = 0; mt < 2; mt++)
#pragma unroll
        for (int i = 0; i < 4; i++) { m_run[mt][i] = -INFINITY; l_run[mt][i] = 0.f; }
#pragma unroll
    for (int mt = 0; mt < 2; mt++)
#pragma unroll
        for (int nt = 0; nt < 4; nt++) oacc[mt][nt] = (f32x4){0.f, 0.f, 0.f, 0.f};

    for (int t = 0; t < 2; t++) {
        f32x4 sacc[2][8];
#pragma unroll
        for (int mt = 0; mt < 2; mt++)
#pragma unroll
            for (int nt = 0; nt < 8; nt++) sacc[mt][nt] = (f32x4){0.f, 0.f, 0.f, 0.f};
#pragma unroll
        for (int nt = 0; nt < 8; nt++) {
#pragma unroll
            for (int kf = 0; kf < 2; kf++) {
                int key = 128 * t + 16 * nt + lr;
                int ab = key * 128 + ((16 * g + 64 * kf) ^ ((key & 7) << 4));
                bf16x8 bfr = *(const bf16x8*)(smem + ab);
#pragma unroll
                for (int mt = 0; mt < 2; mt++)
                    sacc[mt][nt] = MFMA_B16(qf[mt][kf], bfr, sacc[mt][nt]);
            }
        }
#pragma unroll
        for (int mt = 0; mt < 2; mt++) {
#pragma unroll
            for (int i = 0; i < 4; i++) {
                float mx = sacc[mt][0][i];
#pragma unroll
                for (int nt = 1; nt < 8; nt++) mx = fmaxf(mx, sacc[mt][nt][i]);
#pragma unroll
                for (int off = 1; off < 16; off <<= 1) mx = fmaxf(mx, __shfl_xor(mx, off));
                float mnew = fmaxf(m_run[mt][i], mx);
                float corr = __expf(m_run[mt][i] - mnew);
                m_run[mt][i] = mnew;
                int qrow = 32 * w + 16 * mt + 4 * g + i;
                int swq = (qrow & 7) << 4;
                float rs = 0.f;
#pragma unroll
                for (int nt = 0; nt < 8; nt++) {
                    float p = __expf(sacc[mt][nt][i] - mnew);
                    rs += p;
                    int col = lr + 16 * nt;
                    *(ushort*)(smem + 65536 + qrow * 256 + ((2 * col) ^ swq)) = f2bf(p);
                }
#pragma unroll
                for (int off = 1; off < 16; off <<= 1) rs += __shfl_xor(rs, off);
                l_run[mt][i] = l_run[mt][i] * corr + rs;
#pragma unroll
                for (int nt = 0; nt < 4; nt++) oacc[mt][nt][i] *= corr;
            }
        }
        LGKM0();

#pragma unroll
        for (int kf = 0; kf < 4; kf++) {
            bf16x8 pfr[2];
#pragma unroll
            for (int mt = 0; mt < 2; mt++) {
                int qrow = 32 * w + 16 * mt + lr;
                int ab = 65536 + qrow * 256 + ((16 * g + 64 * kf) ^ ((qrow & 7) << 4));
                pfr[mt] = *(const bf16x8*)(smem + ab);
            }
#pragma unroll
            for (int nt = 0; nt < 4; nt++) {
                int d = lr + 16 * nt;
                int bb = 32768 + d * 512 + ((16 * g + 64 * kf + 256 * t) ^ ((d & 7) << 4));
                bf16x8 bfr = *(const bf16x8*)(smem + bb);
#pragma unroll
                for (int mt = 0; mt < 2; mt++)
                    oacc[mt][nt] = MFMA_B16(pfr[mt], bfr, oacc[mt][nt]);
            }
        }
    }
    __syncthreads();

#pragma unroll
    for (int mt = 0; mt < 2; mt++)
#pragma unroll
        for (int i = 0; i < 4; i++) {
            float rl = 1.0f / l_run[mt][i];
            int qrow = 32 * w + 16 * mt + 4 * g + i;
            int swq = (qrow & 7) << 4;
#pragma unroll
            for (int nt = 0; nt < 4; nt++) {
                int col = lr + 16 * nt;
                *(ushort*)(smem + 65536 + qrow * 128 + ((2 * col) ^ swq)) = f2bf(oacc[mt][nt][i] * rl);
            }
        }
    for (int e = tid; e < 8192; e += 512) {
        int k = e >> 7, c = e & 127;
        int ad = c * 128 + ((2 * k) ^ ((c & 7) << 4));
        *(ushort*)(smem + ad) = f2bf(Wro[e]);
    }
    __syncthreads();

#pragma unroll
    for (int mt = 0; mt < 2; mt++) {
        bf16x8 ofr[2];
#pragma unroll
        for (int kf = 0; kf < 2; kf++) {
            int orow = 32 * w + 16 * mt + lr;
            int ab = 65536 + orow * 128 + ((16 * g + 64 * kf) ^ ((orow & 7) << 4));
            ofr[kf] = *(const bf16x8*)(smem + ab);
        }
#pragma unroll
        for (int nt = 0; nt < 8; nt++) {
            f32x4 acc = (f32x4){0.f, 0.f, 0.f, 0.f};
#pragma unroll
            for (int kf = 0; kf < 2; kf++) {
                int c = lr + 16 * nt;
                int bb = c * 128 + ((16 * g + 64 * kf) ^ ((c & 7) << 4));
                bf16x8 bfr = *(const bf16x8*)(smem + bb);
                acc = MFMA_B16(ofr[kf], bfr, acc);
            }
            int col = lr + 16 * nt;
            float brod = bro[col];
#pragma unroll
            for (int i = 0; i < 4; i++) {
                int qrow = 32 * w + 16 * mt + 4 * g + i;
                size_t off = base + (size_t)qrow * 128 + col;
                x[off] = x[off] + acc[i] + brod;
            }
        }
    }
}

// ---------------------------------------------------------------------------
// F (MFMA MLP v6, barrier-free; proven at (64,4)).
// ---------------------------------------------------------------------------
__global__ __launch_bounds__(64, 4) void k_mlp_mfma(
    float* __restrict__ x,
    const float* __restrict__ mn_g, const float* __restrict__ mn_b,
    const ushort* __restrict__ w1F, const ushort* __restrict__ w2F,
    const float* __restrict__ b1, const float* __restrict__ b2)
{
    __shared__ __align__(16) unsigned char smem[5120];
    int l = threadIdx.x;
    int g = l >> 4, lr = l & 15;
    size_t rbase = (size_t)blockIdx.x * 16;

    {
        float gl0 = mn_g[l], gl1 = mn_g[l + 64];
        float el0 = mn_b[l], el1 = mn_b[l + 64];
#pragma unroll
        for (int bb = 0; bb < 4; bb++) {
            float a0[4], a1[4];
#pragma unroll
            for (int rr = 0; rr < 4; rr++) {
                size_t ro = (rbase + 4 * bb + rr) * 128;
                a0[rr] = x[ro + l];
                a1[rr] = x[ro + l + 64];
            }
#pragma unroll
            for (int rr = 0; rr < 4; rr++) {
                int rloc = 4 * bb + rr;
                float x0 = a0[rr], x1 = a1[rr];
                float s = x0 + x1, q = x0 * x0 + x1 * x1;
#pragma unroll
                for (int off = 32; off; off >>= 1) { s += __shfl_xor(s, off); q += __shfl_xor(q, off); }
                float mu = s * (1.0f / 128.0f);
                float var = q * (1.0f / 128.0f) - mu * mu;
                float rs = rsqrtf(var + 1e-5f);
                int sw = (rloc & 7) << 4;
                *(ushort*)(smem + rloc * 256 + ((2 * l) ^ sw))        = f2bf((x0 - mu) * rs * gl0 + el0);
                *(ushort*)(smem + rloc * 256 + ((2 * (l + 64)) ^ sw)) = f2bf((x1 - mu) * rs * gl1 + el1);
            }
        }
    }
    LGKM0();

    bf16x8 afr[4];
#pragma unroll
    for (int kf = 0; kf < 4; kf++) {
        afr[kf] = *(const bf16x8*)(smem + lr * 256 + ((16 * g + 64 * kf) ^ ((lr & 7) << 4)));
    }

    f32x4 oacc[8];
#pragma unroll
    for (int nt = 0; nt < 8; nt++) oacc[nt] = (f32x4){0.f, 0.f, 0.f, 0.f};

#pragma unroll
    for (int kb = 0; kb < 2; kb++) {
#pragma unroll
        for (int cc = 0; cc < 4; cc++) {
#pragma unroll
            for (int nt2 = 0; nt2 < 2; nt2++) {
                int nt = 2 * cc + nt2;
                f32x4 acc = (f32x4){0.f, 0.f, 0.f, 0.f};
#pragma unroll
                for (int kf = 0; kf < 4; kf++) {
                    bf16x8 bfr = *(const bf16x8*)(w1F + (((((kb << 3) | nt) << 2) | kf) << 9) + (l << 3));
                    acc = MFMA_B16(afr[kf], bfr, acc);
                }
                float bb1 = b1[128 * kb + 16 * nt + lr];
                int colc = lr + 16 * nt2;
#pragma unroll
                for (int i = 0; i < 4; i++) {
                    int row = 4 * g + i;
                    int ad = 4096 + row * 64 + ((2 * colc) ^ ((row & 3) << 4));
                    *(ushort*)(smem + ad) = f2bf(fmaxf(acc[i] + bb1, 0.f));
                }
            }
            LGKM0();

            bf16x8 hfr = *(const bf16x8*)(smem + 4096 + lr * 64 + ((16 * g) ^ ((lr & 3) << 4)));
#pragma unroll
            for (int nt = 0; nt < 8; nt++) {
                bf16x8 bfr = *(const bf16x8*)(w2F + (((((kb << 3) | nt) << 2) | cc) << 9) + (l << 3));
                oacc[nt] = MFMA_B16(hfr, bfr, oacc[nt]);
            }
            LGKM0();
        }
    }

#pragma unroll
    for (int nt = 0; nt < 8; nt++) {
        int col = 16 * nt + lr;
#pragma unroll
        for (int i = 0; i < 4; i++) {
            int row = 4 * g + i;
            int ad = row * 256 + ((2 * col) ^ ((row & 7) << 4));
            *(ushort*)(smem + ad) = f2bf(oacc[nt][i]);
        }
    }
    LGKM0();
    {
        float b20 = b2[l], b21 = b2[l + 64];
#pragma unroll
        for (int rr = 0; rr < 16; rr++) {
            int sw = (rr & 7) << 4;
            float d0 = lbf(*(const ushort*)(smem + rr * 256 + ((2 * l) ^ sw)));
            float d1 = lbf(*(const ushort*)(smem + rr * 256 + ((2 * (l + 64)) ^ sw)));
            size_t ro = (rbase + rr) * 128;
            x[ro + l]      = x[ro + l]      + d0 + b20;
            x[ro + l + 64] = x[ro + l + 64] + d1 + b21;
        }
    }
}

// ---------------------------------------------------------------------------
extern "C" void kernel_launch(void* const* d_in, const int* in_sizes, int n_in,
                              void* d_out, int out_size, void* d_ws, size_t ws_size,
                              hipStream_t stream)
{
    const float* seq   = (const float*)d_in[0];
    const float* pair  = (const float*)d_in[1];
    const float* sn_g  = (const float*)d_in[2];
    const float* sn_b  = (const float*)d_in[3];
    const float* Wq    = (const float*)d_in[4];
    const float* Wk    = (const float*)d_in[5];
    const float* Wyq   = (const float*)d_in[6];
    const float* Wyk   = (const float*)d_in[7];
    const float* Wdist = (const float*)d_in[8];
    const float* Wout  = (const float*)d_in[9];
    const float* bout  = (const float*)d_in[10];
    const float* rn_g  = (const float*)d_in[11];
    const float* rn_b  = (const float*)d_in[12];
    const float* Wrq   = (const float*)d_in[13];
    const float* Wrk   = (const float*)d_in[14];
    const float* Wrv   = (const float*)d_in[15];
    const float* brv   = (const float*)d_in[16];
    const float* Wro   = (const float*)d_in[17];
    const float* bro   = (const float*)d_in[18];
    const float* mn_g  = (const float*)d_in[19];
    const float* mn_b  = (const float*)d_in[20];
    const float* W1    = (const float*)d_in[21];
    const float* b1    = (const float*)d_in[22];
    const float* W2    = (const float*)d_in[23];
    const float* b2    = (const float*)d_in[24];
    (void)in_sizes; (void)n_in; (void)out_size;

    float*  x2   = (float*)d_ws;           // 262144 f32
    float*  a2   = x2 + 262144;            // 65536
    float*  c2   = a2 + 65536;             // 65536
    float*  wd2  = c2 + 65536;             // 512
    ushort* wqF  = (ushort*)(wd2 + 512);   // 8192 each
    ushort* wkF  = wqF + 8192;
    ushort* wvF  = wkF + 8192;
    ushort* wroF = wvF + 8192;             // 8192
    ushort* w1F  = wroF + 8192;            // 32768
    ushort* w2F  = w1F + 32768;            // 32768
    ushort* qA   = w2F + 32768;            // 8388608 each (split path only)
    ushort* kBp  = qA + 8388608;
    ushort* vBp  = kBp + 8388608;
    float*  xres = (float*)d_out;

    const size_t WS_NEED_SPLIT = 52103168ull;   // bytes incl. qA/kB/vB
    bool use_split = (ws_size >= WS_NEED_SPLIT);

    k_ln_pool  <<<512,   256, 0, stream>>>(seq, sn_g, sn_b, x2);
    k_proj     <<<512,   128, 0, stream>>>(x2, Wq, Wk, Wyq, Wyk, Wout, bout, a2, c2);
    k_wd2      <<<1,     128, 0, stream>>>(Wdist, Wout, wd2);
    k_wt       <<<64,    512, 0, stream>>>(Wrq, Wrk, Wrv, Wro, wqF, wkF, wvF, wroF);
    k_wt12     <<<128,   512, 0, stream>>>(W1, W2, w1F, w2F);
    if (use_split) {
        k_qkv_asm<<<4096, 64,  0, stream>>>(xres, pair, a2, c2, wd2,
                                            rn_g, rn_b, wqF, wkF, wvF, brv,
                                            qA, kBp, vBp);
        k_attn2  <<<2048, 128, 0, stream>>>(xres, qA, kBp, vBp, wroF, bro);
    } else {
        k_assemble <<<65536, 256, 0, stream>>>(pair, a2, c2, wd2, xres);
        k_attn_mfma<<<512,   512, 0, stream>>>(xres, rn_g, rn_b, wqF, wkF, wvF, brv, Wro, bro);
    }
    k_mlp_mfma <<<8192,  64,  0, stream>>>(xres, mn_g, mn_b, w1F, w2F, b1, b2);
}